// Round 22
// baseline (3560.771 us; speedup 1.0000x reference)
//
#include <hip/hip_runtime.h>
#include <math.h>

#define EPSV 1e-5f

typedef __attribute__((ext_vector_type(8))) short bf16x8;
typedef __attribute__((ext_vector_type(4))) float f32x4;
typedef unsigned short ushort;

__device__ inline ushort f2bf(float x) {
  unsigned u = __builtin_bit_cast(unsigned, x);
  u += 0x7FFFu + ((u >> 16) & 1u);
  return (ushort)(u >> 16);
}

// async global->LDS, 16 bytes per lane; dest = wave-uniform base + lane*16
#define GLOAD16(lptr, gptr)                                              \
  __builtin_amdgcn_global_load_lds(                                      \
      (const __attribute__((address_space(1))) unsigned int*)(gptr),     \
      (__attribute__((address_space(3))) unsigned int*)(lptr), 16, 0, 0)

// ---------------------------------------------------------------------------
// f32 -> bf16 plane conversion (contiguous). n4 = count/4.
// ---------------------------------------------------------------------------
__global__ __launch_bounds__(256) void convh_kernel(
    const float* __restrict__ in, ushort* __restrict__ hi, int n4) {
  int i = blockIdx.x * 256 + threadIdx.x;
  if (i >= n4) return;
  float4 v = ((const float4*)in)[i];
  float vv[4] = {v.x, v.y, v.z, v.w};
  unsigned hw[4];
#pragma unroll
  for (int e = 0; e < 4; ++e) hw[e] = f2bf(vv[e]);
  ((uint2*)hi)[i] = make_uint2(hw[0] | (hw[1] << 16), hw[2] | (hw[3] << 16));
}

// ---------------------------------------------------------------------------
// f32 -> bf16 for all 20 main layers of one weight type, strided dst.
// ---------------------------------------------------------------------------
__global__ __launch_bounds__(256) void convmain_kernel(
    const float* __restrict__ src, ushort* __restrict__ dst, int perLayer4,
    int dstOff4, int n4) {
  int i = blockIdx.x * 256 + threadIdx.x;
  if (i >= n4) return;
  int l = i / perLayer4;
  int r = i - l * perLayer4;
  float4 v = ((const float4*)src)[i];
  float vv[4] = {v.x, v.y, v.z, v.w};
  unsigned hw[4];
#pragma unroll
  for (int e = 0; e < 4; ++e) hw[e] = f2bf(vv[e]);
  ((uint2*)dst)[(size_t)l * 786432 + dstOff4 + r] =
      make_uint2(hw[0] | (hw[1] << 16), hw[2] | (hw[3] << 16));
}

// ---------------------------------------------------------------------------
// Patch embed + pnorm LN v2. Block = (b, n): 16 tokens x 128 ch, 256 thr.
// ---------------------------------------------------------------------------
__global__ __launch_bounds__(256) void patch_ln2_kernel(
    const float* __restrict__ x, const float* __restrict__ pw,
    const float* __restrict__ pbias, const float* __restrict__ nw,
    const float* __restrict__ nb, float* __restrict__ out) {
  int bid = blockIdx.x;  // b*256 + n
  int b = bid >> 8, n = bid & 255;
  int py = (n >> 4) * 16, px0 = (n & 15) * 16;
  __shared__ float xin[3][16][16];
  __shared__ float wls[128][52];
  __shared__ float pbs[128];
  int tid = threadIdx.x;
  if (tid < 192) {
    int ci = tid / 64, rr = (tid % 64) >> 2, c4 = tid & 3;
    const float* src =
        x + ((size_t)(b * 3 + ci) * 256 + (py + rr)) * 256 + px0 + c4 * 4;
    *(float4*)&xin[ci][rr][c4 * 4] = *(const float4*)src;
  }
  for (int idx = tid; idx < 6144; idx += 256) {
    int c = idx / 48, q = idx % 48;
    wls[c][q] = pw[c * 48 + q];
  }
  if (tid < 128) pbs[tid] = pbias[tid];
  __syncthreads();

  int tt = tid >> 4, cg = tid & 15;
  int ii = tt >> 2, jj = tt & 3;
  float xv[48];
#pragma unroll
  for (int ci = 0; ci < 3; ++ci)
#pragma unroll
    for (int dy = 0; dy < 4; ++dy)
#pragma unroll
      for (int dx = 0; dx < 4; ++dx)
        xv[ci * 16 + dy * 4 + dx] = xin[ci][ii * 4 + dy][jj * 4 + dx];

  float o[8];
#pragma unroll
  for (int e = 0; e < 8; ++e) {
    int c = cg + e * 16;
    float a = pbs[c];
#pragma unroll
    for (int q4 = 0; q4 < 12; ++q4) {
      float4 w4 = *(const float4*)&wls[c][q4 * 4];
      a += w4.x * xv[q4 * 4] + w4.y * xv[q4 * 4 + 1] + w4.z * xv[q4 * 4 + 2] +
           w4.w * xv[q4 * 4 + 3];
    }
    o[e] = a;
  }
  float s = 0.f;
#pragma unroll
  for (int e = 0; e < 8; ++e) s += o[e];
#pragma unroll
  for (int off = 8; off > 0; off >>= 1) s += __shfl_xor(s, off, 16);
  float mean = s * (1.0f / 128.0f);
  float sq = 0.f;
#pragma unroll
  for (int e = 0; e < 8; ++e) {
    float d = o[e] - mean;
    sq += d * d;
  }
#pragma unroll
  for (int off = 8; off > 0; off >>= 1) sq += __shfl_xor(sq, off, 16);
  float rstd = rsqrtf(sq * (1.0f / 128.0f) + EPSV);
  size_t base = ((size_t)bid * 16 + tt) * 128;
#pragma unroll
  for (int e = 0; e < 8; ++e) {
    int c = cg + e * 16;
    out[base + c] = (o[e] - mean) * rstd * nw[c] + nb[c];
  }
}

// ---------------------------------------------------------------------------
// LayerNorm over C (128/256), one wave per row, 4 rows/block -> bf16 plane.
// ---------------------------------------------------------------------------
template <int C>
__global__ __launch_bounds__(256) void lnC_kernel(
    const float* __restrict__ X, const float* __restrict__ w,
    const float* __restrict__ bb, ushort* __restrict__ outH) {
  constexpr int NV = C / 64;
  int wave = threadIdx.x >> 6, lane = threadIdx.x & 63;
  int row = blockIdx.x * 4 + wave;
  const float* xr = X + (size_t)row * C + lane * NV;
  float v[NV];
  if (NV == 2) {
    float2 t2 = *(const float2*)xr;
    v[0] = t2.x; v[1] = t2.y;
  } else {
#pragma unroll
    for (int q = 0; q < NV; q += 4) {
      float4 t4 = *(const float4*)(xr + q);
      v[q] = t4.x; v[q + 1] = t4.y; v[q + 2] = t4.z; v[q + 3] = t4.w;
    }
  }
  float s = 0.f;
#pragma unroll
  for (int q = 0; q < NV; ++q) s += v[q];
#pragma unroll
  for (int o = 32; o > 0; o >>= 1) s += __shfl_xor(s, o, 64);
  float mean = s * (1.0f / C);
  float sq = 0.f;
#pragma unroll
  for (int q = 0; q < NV; ++q) {
    float d = v[q] - mean;
    sq += d * d;
  }
#pragma unroll
  for (int o = 32; o > 0; o >>= 1) sq += __shfl_xor(sq, o, 64);
  float rstd = rsqrtf(sq * (1.0f / C) + EPSV);
#pragma unroll
  for (int q = 0; q < NV; ++q) {
    int c = lane * NV + q;
    outH[(size_t)row * C + c] = f2bf((v[q] - mean) * rstd * w[c] + bb[c]);
  }
}

// ---------------------------------------------------------------------------
// Patch merge gather + LN -> bf16 plane.
// ---------------------------------------------------------------------------
template <int MODE>
__global__ __launch_bounds__(256) void merge_ln_kernel(
    const float* __restrict__ Xin, const float* __restrict__ nw,
    const float* __restrict__ nb, ushort* __restrict__ outH) {
  constexpr int CM = MODE ? 1024 : 512;
  constexpr int NE = CM / 256;
  int ot = blockIdx.x;
  int tid = threadIdx.x;
  __shared__ float redA[4];
  __shared__ float redB[4];

  float v[NE];
#pragma unroll
  for (int e = 0; e < NE; ++e) {
    int cp = tid + e * 256;
    if (MODE == 0) {
      int b = ot >> 10, r = ot & 1023;
      int n = r >> 2, di = (r >> 1) & 1, dj = r & 1;
      int q = cp >> 7, c = cp & 127;
      int i = 2 * di + (q & 1), j = 2 * dj + (q >> 1);
      v[e] = Xin[((b * 256 + n) * 16 + i * 4 + j) * 128 + c];
    } else {
      int b = ot >> 8, n = ot & 255;
      int q = cp >> 8, c = cp & 255;
      int di = q & 1, dj = q >> 1;
      v[e] = Xin[((b * 256 + n) * 4 + di * 2 + dj) * 256 + c];
    }
  }
  float s = 0.f;
#pragma unroll
  for (int e = 0; e < NE; ++e) s += v[e];
#pragma unroll
  for (int o = 32; o > 0; o >>= 1) s += __shfl_xor(s, o, 64);
  if ((tid & 63) == 0) redA[tid >> 6] = s;
  __syncthreads();
  float mean = (redA[0] + redA[1] + redA[2] + redA[3]) * (1.0f / CM);
  float sq = 0.f;
#pragma unroll
  for (int e = 0; e < NE; ++e) {
    float d = v[e] - mean;
    sq += d * d;
  }
#pragma unroll
  for (int o = 32; o > 0; o >>= 1) sq += __shfl_xor(sq, o, 64);
  if ((tid & 63) == 0) redB[tid >> 6] = sq;
  __syncthreads();
  float var = (redB[0] + redB[1] + redB[2] + redB[3]) * (1.0f / CM);
  float rstd = rsqrtf(var + EPSV);
#pragma unroll
  for (int e = 0; e < NE; ++e) {
    int cp = tid + e * 256;
    outH[(size_t)ot * CM + cp] = f2bf((v[e] - mean) * rstd * nw[cp] + nb[cp]);
  }
}

// ---------------------------------------------------------------------------
// bf16 MFMA GEMM v5: BK=64, XOR-swizzled LDS, LDS-staged vectorized epilogue.
// EP 0: bias->f32. EP 1: +pos->f32. EP 2: +extra->f32 (residual).
// EP 3: gelu->bf16. EP 4: qkv->bf16 (Q cols x0.125).
// EP 5: residual->f32 AND fused next-block LN->bf16 (requires N==128, nb==1).
// ---------------------------------------------------------------------------
template <int EP, int BM>
__global__ __launch_bounds__(256) void mgemm4_kernel(
    const ushort* __restrict__ Ah, const ushort* __restrict__ Wh,
    const float* __restrict__ bias, const float* __restrict__ extra,
    float* __restrict__ outF, ushort* __restrict__ outH,
    const float* __restrict__ lnw, const float* __restrict__ lnb, int M, int N,
    int K) {
  constexpr int NI = BM / 32;
  constexpr int ASH = BM * 64;  // A tile shorts
  constexpr int LSZ = (ASH + 8192 > BM * 136) ? (ASH + 8192) : (BM * 136);
  __shared__ __align__(16) ushort Lds[LSZ];
  int nb = N >> 7;
  int bx = blockIdx.x % nb, by = blockIdx.x / nb;
  int tid = threadIdx.x;
  int wv = tid >> 6, lane = tid & 63;
  int srow = tid >> 3;
  int scol = ((tid & 7) ^ (srow & 7)) << 3;  // source-side swizzle (shorts)
  const ushort* aS = Ah + (size_t)(by * BM + srow) * K + scol;
  const ushort* wS = Wh + (size_t)(bx * 128 + srow) * K + scol;
  ushort* dA = Lds + wv * 512;
  ushort* dW = Lds + ASH + wv * 512;

  int wm = (wv >> 1) * (BM / 2), wn = (wv & 1) * 64;
  int fr = lane & 15, fq = lane >> 4;
  int rsw = fr & 7;  // read-side swizzle key

  f32x4 acc[NI][4];
#pragma unroll
  for (int i = 0; i < NI; ++i)
#pragma unroll
    for (int j = 0; j < 4; ++j) acc[i][j] = {0.f, 0.f, 0.f, 0.f};

  for (int k0 = 0; k0 < K; k0 += 64) {
#pragma unroll
    for (int q = 0; q < BM / 32; ++q)
      GLOAD16(dA + q * 2048, aS + (size_t)q * 32 * K + k0);
#pragma unroll
    for (int q = 0; q < 4; ++q)
      GLOAD16(dW + q * 2048, wS + (size_t)q * 32 * K + k0);
    __syncthreads();

#pragma unroll
    for (int kh = 0; kh < 2; ++kh) {
      bf16x8 fa[NI], fb[4];
#pragma unroll
      for (int i = 0; i < NI; ++i) {
        int row = wm + i * 16 + fr;
        fa[i] = *(const bf16x8*)(Lds + row * 64 + ((((kh << 2) + fq) ^ rsw) << 3));
      }
#pragma unroll
      for (int j = 0; j < 4; ++j) {
        int row = wn + j * 16 + fr;
        fb[j] = *(const bf16x8*)(Lds + ASH + row * 64 +
                                 ((((kh << 2) + fq) ^ rsw) << 3));
      }
#pragma unroll
      for (int i = 0; i < NI; ++i)
#pragma unroll
        for (int j = 0; j < 4; ++j)
          acc[i][j] = __builtin_amdgcn_mfma_f32_16x16x32_bf16(fa[i], fb[j],
                                                              acc[i][j], 0, 0,
                                                              0);
    }
    __syncthreads();
  }

  int row0 = by * BM;
  int col0 = bx * 128;
  if (EP == 3 || EP == 4) {
    ushort* LdsO = Lds;
#pragma unroll
    for (int j = 0; j < 4; ++j) {
      int col = wn + j * 16 + fr;
      float bvv = bias ? bias[col0 + col] : 0.f;
      bool sc = (EP == 4) && (col0 + col < 512);
#pragma unroll
      for (int i = 0; i < NI; ++i) {
#pragma unroll
        for (int e = 0; e < 4; ++e) {
          int rl = wm + i * 16 + fq * 4 + e;
          float o = acc[i][j][e] + bvv;
          if (EP == 3)
            o = 0.5f * o * (1.0f + erff(o * 0.70710678118654752f));
          else if (sc)
            o *= 0.125f;
          LdsO[rl * 136 + col] = f2bf(o);
        }
      }
    }
    __syncthreads();
#pragma unroll
    for (int p = 0; p < BM / 16; ++p) {
      int ch = p * 256 + tid;
      int r = ch >> 4, cc = (ch & 15) * 8;
      *(uint4*)&outH[(size_t)(row0 + r) * N + col0 + cc] =
          *(const uint4*)&LdsO[r * 136 + cc];
    }
  } else {
    float* LdsF = (float*)Lds;
    int strip = wv >> 1;
#pragma unroll
    for (int i = 0; i < NI; ++i) {
#pragma unroll
      for (int j = 0; j < 4; ++j) {
        int col = wn + j * 16 + fr;
        float bvv = bias ? bias[col0 + col] : 0.f;
#pragma unroll
        for (int e = 0; e < 4; ++e)
          LdsF[(strip * 16 + fq * 4 + e) * 136 + col] = acc[i][j][e] + bvv;
      }
      __syncthreads();
#pragma unroll
      for (int p = 0; p < 4; ++p) {
        int c = p * 256 + tid;  // 0..1023
        int st = c >> 9;
        int rem = c & 511;
        int r = rem >> 5, cc = (rem & 31) * 4;
        int grow = row0 + st * (BM / 2) + i * 16 + r;
        float4 v = *(const float4*)&LdsF[(st * 16 + r) * 136 + cc];
        if (EP == 1) {
          float4 e4 =
              *(const float4*)&extra[(size_t)(grow & 255) * N + col0 + cc];
          v.x += e4.x; v.y += e4.y; v.z += e4.z; v.w += e4.w;
        } else if (EP == 2 || EP == 5) {
          float4 e4 = *(const float4*)&extra[(size_t)grow * N + col0 + cc];
          v.x += e4.x; v.y += e4.y; v.z += e4.z; v.w += e4.w;
        }
        *(float4*)&outF[(size_t)grow * N + col0 + cc] = v;
        if (EP == 5) {
          // fused next-block LN (N==128, nb==1): each row's 128 cols live in
          // a 32-lane group (threads r*32..r*32+31 of this wave).
          float s1 = v.x + v.y + v.z + v.w;
#pragma unroll
          for (int o = 16; o > 0; o >>= 1) s1 += __shfl_xor(s1, o, 32);
          float mean = s1 * (1.0f / 128.0f);
          float dx = v.x - mean, dy = v.y - mean, dz = v.z - mean,
                dw = v.w - mean;
          float s2 = dx * dx + dy * dy + dz * dz + dw * dw;
#pragma unroll
          for (int o = 16; o > 0; o >>= 1) s2 += __shfl_xor(s2, o, 32);
          float rstd = rsqrtf(s2 * (1.0f / 128.0f) + EPSV);
          unsigned h0 = f2bf(dx * rstd * lnw[cc] + lnb[cc]);
          unsigned h1 = f2bf(dy * rstd * lnw[cc + 1] + lnb[cc + 1]);
          unsigned h2 = f2bf(dz * rstd * lnw[cc + 2] + lnb[cc + 2]);
          unsigned h3 = f2bf(dw * rstd * lnw[cc + 3] + lnb[cc + 3]);
          *(uint2*)&outH[(size_t)grow * N + cc] =
              make_uint2(h0 | (h1 << 16), h2 | (h3 << 16));
        }
      }
      __syncthreads();
    }
  }
}

// ---------------------------------------------------------------------------
// Stem-1 f2 GEMM, BN=256 single column tile (BM=64), fused residual + LN.
// out f32 -> Xa; if outH: LN(out) bf16 -> outH (next block's f1 input).
// LDS: K-loop A 8KB + W 32KB = 40KB; epilogue strips [32][264] f32 = 33KB.
// Each row's 256 cols span one wave -> width-64 shfl LN (matches lnC<256>).
// ---------------------------------------------------------------------------
__global__ __launch_bounds__(256) void mgemm6_kernel(
    const ushort* __restrict__ Ah, const ushort* __restrict__ Wh,
    const float* __restrict__ bias, const float* __restrict__ extra,
    float* __restrict__ outF, ushort* __restrict__ outH,
    const float* __restrict__ lnw, const float* __restrict__ lnb, int M,
    int K) {
  constexpr int ASH = 64 * 64;    // 4096 shorts
  constexpr int WSH = 256 * 64;   // 16384 shorts
  __shared__ __align__(16) ushort Lds[ASH + WSH];  // 40 KB
  int by = blockIdx.x;
  int tid = threadIdx.x;
  int wv = tid >> 6, lane = tid & 63;
  int fr = lane & 15, fq = lane >> 4;
  int srow = tid >> 3;
  int scol = ((tid & 7) ^ (srow & 7)) << 3;
  const ushort* aS = Ah + (size_t)(by * 64 + srow) * K + scol;
  const ushort* wS = Wh + (size_t)srow * K + scol;
  ushort* dA = Lds + wv * 512;
  ushort* dW = Lds + ASH + wv * 512;

  f32x4 acc[4][4];  // [row frag i][col frag j within wave's 64 cols]
#pragma unroll
  for (int i = 0; i < 4; ++i)
#pragma unroll
    for (int j = 0; j < 4; ++j) acc[i][j] = {0.f, 0.f, 0.f, 0.f};

  for (int k0 = 0; k0 < K; k0 += 64) {
    GLOAD16(dA, aS + k0);
    GLOAD16(dA + 2048, aS + (size_t)32 * K + k0);
#pragma unroll
    for (int q = 0; q < 8; ++q)
      GLOAD16(dW + q * 2048, wS + (size_t)q * 32 * K + k0);
    __syncthreads();
#pragma unroll
    for (int kh = 0; kh < 2; ++kh) {
      bf16x8 fa[4], fb[4];
#pragma unroll
      for (int i = 0; i < 4; ++i) {
        int row = i * 16 + fr;
        fa[i] = *(const bf16x8*)(Lds + row * 64 +
                                 ((((kh << 2) + fq) ^ (row & 7)) << 3));
      }
#pragma unroll
      for (int j = 0; j < 4; ++j) {
        int row = wv * 64 + j * 16 + fr;
        fb[j] = *(const bf16x8*)(Lds + ASH + row * 64 +
                                 ((((kh << 2) + fq) ^ (row & 7)) << 3));
      }
#pragma unroll
      for (int i = 0; i < 4; ++i)
#pragma unroll
        for (int j = 0; j < 4; ++j)
          acc[i][j] = __builtin_amdgcn_mfma_f32_16x16x32_bf16(fa[i], fb[j],
                                                              acc[i][j], 0, 0,
                                                              0);
    }
    __syncthreads();
  }

  int row0 = by * 64;
  float* LdsF = (float*)Lds;
#pragma unroll
  for (int half = 0; half < 2; ++half) {
    // stage rows half*32 .. half*32+31 (i = 2*half, 2*half+1)
#pragma unroll
    for (int ii = 0; ii < 2; ++ii) {
      int i = half * 2 + ii;
#pragma unroll
      for (int j = 0; j < 4; ++j) {
        int col = wv * 64 + j * 16 + fr;
        float bvv = bias[col];
#pragma unroll
        for (int e = 0; e < 4; ++e)
          LdsF[(ii * 16 + fq * 4 + e) * 264 + col] = acc[i][j][e] + bvv;
      }
    }
    __syncthreads();
    // vector pass: 8 passes x 4 rows; row = one wave (64 lanes x float4)
#pragma unroll
    for (int p = 0; p < 8; ++p) {
      int rl = p * 4 + (tid >> 6);  // 0..31 local
      int grow = row0 + half * 32 + rl;
      int cc = lane * 4;
      float4 v = *(const float4*)&LdsF[rl * 264 + cc];
      float4 e4 = *(const float4*)&extra[(size_t)grow * 256 + cc];
      v.x += e4.x; v.y += e4.y; v.z += e4.z; v.w += e4.w;
      *(float4*)&outF[(size_t)grow * 256 + cc] = v;
      if (outH) {
        float s1 = v.x + v.y + v.z + v.w;
#pragma unroll
        for (int o = 32; o > 0; o >>= 1) s1 += __shfl_xor(s1, o, 64);
        float mean = s1 * (1.0f / 256.0f);
        float dx = v.x - mean, dy = v.y - mean, dz = v.z - mean,
              dw = v.w - mean;
        float s2 = dx * dx + dy * dy + dz * dz + dw * dw;
#pragma unroll
        for (int o = 32; o > 0; o >>= 1) s2 += __shfl_xor(s2, o, 64);
        float rstd = rsqrtf(s2 * (1.0f / 256.0f) + EPSV);
        unsigned h0 = f2bf(dx * rstd * lnw[cc] + lnb[cc]);
        unsigned h1 = f2bf(dy * rstd * lnw[cc + 1] + lnb[cc + 1]);
        unsigned h2 = f2bf(dz * rstd * lnw[cc + 2] + lnb[cc + 2]);
        unsigned h3 = f2bf(dw * rstd * lnw[cc + 3] + lnb[cc + 3]);
        *(uint2*)&outH[(size_t)grow * 256 + cc] =
            make_uint2(h0 | (h1 << 16), h2 | (h3 << 16));
      }
    }
    __syncthreads();
  }
}

// ---------------------------------------------------------------------------
// Fused MFMA attention: scores + softmax + PV in one kernel.
// Block = (b, h, 64 q-rows), grid 512, 256 thr. LDS ~77 KB -> 2 blocks/CU.
// ---------------------------------------------------------------------------
__global__ __launch_bounds__(256) void attn_fused2_kernel(
    const ushort* __restrict__ qkvh, const float* __restrict__ rpb,
    const int* __restrict__ rpe, ushort* __restrict__ outH) {
  int bid = blockIdx.x;
  int qc = bid & 3, bh = bid >> 2;
  int b = bh >> 3, h = bh & 7;
  int n0 = qc * 64;
  int tid = threadIdx.x;
  int wv = tid >> 6, lane = tid & 63;
  int fr = lane & 15, fq = lane >> 4;
  __shared__ __align__(16) ushort Qs[64 * 64];
  __shared__ __align__(16) ushort Ks[256 * 64];   // K, then P [64][256]
  __shared__ __align__(16) ushort Vt[64 * 256];
  __shared__ float rpbh[961];
  __shared__ float red[64][4];

  int srow = tid >> 3;
  int sc = ((tid & 7) ^ (srow & 7)) << 3;
  const ushort* Qg = qkvh + (size_t)(b * 256 + n0 + srow) * 1536 + h * 64 + sc;
  GLOAD16(Qs + wv * 512, Qg);
  GLOAD16(Qs + 2048 + wv * 512, Qg + (size_t)32 * 1536);
  const ushort* Kg = qkvh + (size_t)(b * 256 + srow) * 1536 + 512 + h * 64 + sc;
#pragma unroll
  for (int q = 0; q < 8; ++q)
    GLOAD16(Ks + q * 2048 + wv * 512, Kg + (size_t)q * 32 * 1536);
#pragma unroll
  for (int pass = 0; pass < 4; ++pass) {
    int m = pass * 64 + (tid >> 2);
    int sg = (tid & 3) * 16;
    const ushort* Vg = qkvh + (size_t)(b * 256 + m) * 1536 + 1024 + h * 64 + sg;
    ushort tmp[16];
    *(uint4*)tmp = *(const uint4*)Vg;
    *(uint4*)(tmp + 8) = *(const uint4*)(Vg + 8);
    int ch = m >> 3, ml = m & 7;
#pragma unroll
    for (int e = 0; e < 16; ++e) {
      int d = sg + e;
      int cs = (ch & 24) | ((ch & 7) ^ (d & 7));
      Vt[d * 256 + cs * 8 + ml] = tmp[e];
    }
  }
  for (int i = tid; i < 961; i += 256) rpbh[i] = rpb[i * 8 + h];
  __syncthreads();

  f32x4 acc[4][4];
#pragma unroll
  for (int i = 0; i < 4; ++i)
#pragma unroll
    for (int j = 0; j < 4; ++j) acc[i][j] = {0.f, 0.f, 0.f, 0.f};
#pragma unroll
  for (int kh = 0; kh < 2; ++kh) {
    bf16x8 fa[4], fb[4];
#pragma unroll
    for (int i = 0; i < 4; ++i) {
      int row = i * 16 + fr;
      fa[i] = *(const bf16x8*)(Qs + row * 64 +
                               ((((kh << 2) + fq) ^ (row & 7)) << 3));
    }
#pragma unroll
    for (int j = 0; j < 4; ++j) {
      int row = wv * 64 + j * 16 + fr;
      fb[j] = *(const bf16x8*)(Ks + row * 64 +
                               ((((kh << 2) + fq) ^ (row & 7)) << 3));
    }
#pragma unroll
    for (int i = 0; i < 4; ++i)
#pragma unroll
      for (int j = 0; j < 4; ++j)
        acc[i][j] = __builtin_amdgcn_mfma_f32_16x16x32_bf16(fa[i], fb[j],
                                                            acc[i][j], 0, 0, 0);
  }

  float sreg[4][4][4];  // [i][j][e]
#pragma unroll
  for (int i = 0; i < 4; ++i)
#pragma unroll
    for (int e = 0; e < 4; ++e) {
      int n = n0 + i * 16 + fq * 4 + e;
#pragma unroll
      for (int j = 0; j < 4; ++j) {
        int m = wv * 64 + j * 16 + fr;
        sreg[i][j][e] = acc[i][j][e] + rpbh[rpe[n * 256 + m]];
      }
    }

  float rmax[4][4];
#pragma unroll
  for (int i = 0; i < 4; ++i)
#pragma unroll
    for (int e = 0; e < 4; ++e) {
      float mx = fmaxf(fmaxf(sreg[i][0][e], sreg[i][1][e]),
                       fmaxf(sreg[i][2][e], sreg[i][3][e]));
#pragma unroll
      for (int o = 8; o > 0; o >>= 1) mx = fmaxf(mx, __shfl_xor(mx, o, 16));
      if (fr == 0) red[i * 16 + fq * 4 + e][wv] = mx;
    }
  __syncthreads();  // also: all K reads complete beyond this point
#pragma unroll
  for (int i = 0; i < 4; ++i)
#pragma unroll
    for (int e = 0; e < 4; ++e) {
      int row = i * 16 + fq * 4 + e;
      rmax[i][e] = fmaxf(fmaxf(red[row][0], red[row][1]),
                         fmaxf(red[row][2], red[row][3]));
    }
  __syncthreads();
  float rinv[4][4];
#pragma unroll
  for (int i = 0; i < 4; ++i)
#pragma unroll
    for (int e = 0; e < 4; ++e) {
      float sm = 0.f;
#pragma unroll
      for (int j = 0; j < 4; ++j) {
        sreg[i][j][e] = expf(sreg[i][j][e] - rmax[i][e]);
        sm += sreg[i][j][e];
      }
#pragma unroll
      for (int o = 8; o > 0; o >>= 1) sm += __shfl_xor(sm, o, 16);
      if (fr == 0) red[i * 16 + fq * 4 + e][wv] = sm;
    }
  __syncthreads();
#pragma unroll
  for (int i = 0; i < 4; ++i)
#pragma unroll
    for (int e = 0; e < 4; ++e) {
      int row = i * 16 + fq * 4 + e;
      rinv[i][e] =
          1.0f / (red[row][0] + red[row][1] + red[row][2] + red[row][3]);
    }
  ushort* Ps = Ks;
#pragma unroll
  for (int i = 0; i < 4; ++i)
#pragma unroll
    for (int e = 0; e < 4; ++e) {
      int qrow = i * 16 + fq * 4 + e;
#pragma unroll
      for (int j = 0; j < 4; ++j) {
        int m = wv * 64 + j * 16 + fr;
        int ch = m >> 3, t = m & 7;
        int cs = (ch & 24) | ((ch & 7) ^ (qrow & 7));
        Ps[qrow * 256 + cs * 8 + t] = f2bf(sreg[i][j][e] * rinv[i][e]);
      }
    }
  __syncthreads();

  f32x4 pacc[4];
#pragma unroll
  for (int i = 0; i < 4; ++i) pacc[i] = {0.f, 0.f, 0.f, 0.f};
  int dbase = wv * 16;
#pragma unroll
  for (int ks = 0; ks < 8; ++ks) {
    int ch = (ks << 2) + fq;
    bf16x8 fb;
    {
      int row = dbase + fr;
      int cs = (ch & 24) | ((ch & 7) ^ (row & 7));
      fb = *(const bf16x8*)(Vt + row * 256 + cs * 8);
    }
    bf16x8 fa[4];
#pragma unroll
    for (int i = 0; i < 4; ++i) {
      int row = i * 16 + fr;
      int cs = (ch & 24) | ((ch & 7) ^ (row & 7));
      fa[i] = *(const bf16x8*)(Ps + row * 256 + cs * 8);
    }
#pragma unroll
    for (int i = 0; i < 4; ++i)
      pacc[i] = __builtin_amdgcn_mfma_f32_16x16x32_bf16(fa[i], fb, pacc[i], 0,
                                                        0, 0);
  }
#pragma unroll
  for (int i = 0; i < 4; ++i)
#pragma unroll
    for (int e = 0; e < 4; ++e) {
      int q = i * 16 + fq * 4 + e;
      outH[(size_t)(b * 256 + n0 + q) * 512 + h * 64 + dbase + fr] =
          f2bf(pacc[i][e]);
    }
}

// ---------------------------------------------------------------------------
// LayerNorm over 512, wave per row, 4 rows/block. HL=0 f32, HL=1 bf16 plane.
// ---------------------------------------------------------------------------
template <int HL>
__global__ __launch_bounds__(256) void ln512_kernel(
    const float* __restrict__ X, const float* __restrict__ w,
    const float* __restrict__ bb, float* __restrict__ outF,
    ushort* __restrict__ outH) {
  int row = blockIdx.x * 4 + (threadIdx.x >> 6);
  int t = threadIdx.x & 63;
  const float4* xr = (const float4*)(X + (size_t)row * 512);
  float4 v0 = xr[t * 2], v1 = xr[t * 2 + 1];
  float s = v0.x + v0.y + v0.z + v0.w + v1.x + v1.y + v1.z + v1.w;
#pragma unroll
  for (int o = 32; o > 0; o >>= 1) s += __shfl_xor(s, o, 64);
  float mean = s * (1.0f / 512.0f);
  float dv[8] = {v0.x - mean, v0.y - mean, v0.z - mean, v0.w - mean,
                 v1.x - mean, v1.y - mean, v1.z - mean, v1.w - mean};
  float sq = 0.f;
#pragma unroll
  for (int e = 0; e < 8; ++e) sq += dv[e] * dv[e];
#pragma unroll
  for (int o = 32; o > 0; o >>= 1) sq += __shfl_xor(sq, o, 64);
  float rstd = rsqrtf(sq * (1.0f / 512.0f) + EPSV);
  int c = t * 8;
  float ov[8];
#pragma unroll
  for (int e = 0; e < 8; ++e) ov[e] = dv[e] * rstd * w[c + e] + bb[c + e];
  if (HL == 0) {
    float4 o0 = {ov[0], ov[1], ov[2], ov[3]};
    float4 o1 = {ov[4], ov[5], ov[6], ov[7]};
    ((float4*)(outF + (size_t)row * 512))[t * 2] = o0;
    ((float4*)(outF + (size_t)row * 512))[t * 2 + 1] = o1;
  } else {
    __align__(16) ushort h8[8];
#pragma unroll
    for (int e = 0; e < 8; ++e) h8[e] = f2bf(ov[e]);
    *(bf16x8*)(outH + (size_t)row * 512 + c) = *(bf16x8*)h8;
  }
}

// ---------------------------------------------------------------------------
extern "C" void kernel_launch(void* const* d_in, const int* in_sizes, int n_in,
                              void* d_out, int out_size, void* d_ws,
                              size_t ws_size, hipStream_t stream) {
  const float* x = (const float*)d_in[0];
  const float* patch_w = (const float*)d_in[1];
  const float* patch_b = (const float*)d_in[2];
  const float* pnorm_w = (const float*)d_in[3];
  const float* pnorm_b = (const float*)d_in[4];
  const float* s0_n2w = (const float*)d_in[5];
  const float* s0_n2b = (const float*)d_in[6];
  const float* s0_f1w = (const float*)d_in[7];
  const float* s0_f1b = (const float*)d_in[8];
  const float* s0_f2w = (const float*)d_in[9];
  const float* s0_f2b = (const float*)d_in[10];
  const float* m0_nw = (const float*)d_in[11];
  const float* m0_nb = (const float*)d_in[12];
  const float* m0_rw = (const float*)d_in[13];
  const float* s1_n2w = (const float*)d_in[14];
  const float* s1_n2b = (const float*)d_in[15];
  const float* s1_f1w = (const float*)d_in[16];
  const float* s1_f1b = (const float*)d_in[17];
  const float* s1_f2w = (const float*)d_in[18];
  const float* s1_f2b = (const float*)d_in[19];
  const float* m1_nw = (const float*)d_in[20];
  const float* m1_nb = (const float*)d_in[21];
  const float* m1_rw = (const float*)d_in[22];
  const float* pos_embed = (const float*)d_in[23];
  const float* mb_n1w = (const float*)d_in[24];
  const float* mb_n1b = (const float*)d_in[25];
  const float* mb_qkvw = (const float*)d_in[26];
  const float* mb_qkvb = (const float*)d_in[27];
  const float* mb_rpb = (const float*)d_in[28];
  const float* mb_projw = (const float*)d_in[29];
  const float* mb_projb = (const float*)d_in[30];
  const float* mb_n2w = (const float*)d_in[31];
  const float* mb_n2b = (const float*)d_in[32];
  const float* mb_f1w = (const float*)d_in[33];
  const float* mb_f1b = (const float*)d_in[34];
  const float* mb_f2w = (const float*)d_in[35];
  const float* mb_f2b = (const float*)d_in[36];
  const float* fnorm_w = (const float*)d_in[37];
  const float* fnorm_b = (const float*)d_in[38];
  const int* rpe = (const int*)d_in[39];

  // Workspace (235 MB of ~320 MiB):
  float* Xa = (float*)d_ws;
  ushort* BufB = (ushort*)(Xa + 8388608);
  ushort* BufC = (ushort*)(Xa + 12582912);
  ushort* Qkvh = BufC;
  ushort* F1h = BufC + 14680064;
  ushort* Wall = (ushort*)(Xa + 25165824);
  ushort* WallBig = (ushort*)(Xa + 27262976);

#define CONVH(src, cnt, dh)                                              \
  convh_kernel<<<((cnt) / 4 + 255) / 256, 256, 0, stream>>>(src, dh, (cnt) / 4)

  // Pre-convert ALL 20 main layers' weights (one pass per weight type).
  convmain_kernel<<<(20 * 196608 + 255) / 256, 256, 0, stream>>>(
      mb_qkvw, WallBig, 196608, 0, 20 * 196608);
  convmain_kernel<<<(20 * 65536 + 255) / 256, 256, 0, stream>>>(
      mb_projw, WallBig, 65536, 196608, 20 * 65536);
  convmain_kernel<<<(20 * 262144 + 255) / 256, 256, 0, stream>>>(
      mb_f1w, WallBig, 262144, 262144, 20 * 262144);
  convmain_kernel<<<(20 * 262144 + 255) / 256, 256, 0, stream>>>(
      mb_f2w, WallBig, 262144, 524288, 20 * 262144);

  // Patch embed + pnorm LN -> Xa [65536,128]
  patch_ln2_kernel<<<4096, 256, 0, stream>>>(x, patch_w, patch_b, pnorm_w,
                                             pnorm_b, Xa);

  // Stem stage 0: 8 MLP blocks, dim 128, hidden 384.
  // LN for block 0 standalone; LN for blocks 1..7 fused into f2 EP5.
  CONVH(s0_f1w, 8 * 49152, Wall);
  CONVH(s0_f2w, 8 * 49152, Wall + 393216);
  lnC_kernel<128><<<65536 / 4, 256, 0, stream>>>(Xa, s0_n2w, s0_n2b, BufB);
  for (int i = 0; i < 8; ++i) {
    mgemm4_kernel<3, 128><<<(65536 / 128) * (384 / 128), 256, 0, stream>>>(
        BufB, Wall + i * 49152, s0_f1b + i * 384, nullptr, nullptr, BufC,
        nullptr, nullptr, 65536, 384, 128);
    if (i < 7) {
      mgemm4_kernel<5, 64><<<(65536 / 64) * (128 / 128), 256, 0, stream>>>(
          BufC, Wall + 393216 + i * 49152, s0_f2b + i * 128, Xa, Xa, BufB,
          s0_n2w + (i + 1) * 128, s0_n2b + (i + 1) * 128, 65536, 128, 384);
    } else {
      mgemm4_kernel<2, 64><<<(65536 / 64) * (128 / 128), 256, 0, stream>>>(
          BufC, Wall + 393216 + i * 49152, s0_f2b + i * 128, Xa, Xa, nullptr,
          nullptr, nullptr, 65536, 128, 384);
    }
  }
  // Merge 0 -> BufB [16384,512] bf16 -> GEMM -> Xa [16384,256]
  merge_ln_kernel<0><<<16384, 256, 0, stream>>>(Xa, m0_nw, m0_nb, BufB);
  CONVH(m0_rw, 131072, Wall);
  mgemm4_kernel<0, 128><<<(16384 / 128) * (256 / 128), 256, 0, stream>>>(
      BufB, Wall, nullptr, nullptr, Xa, nullptr, nullptr, nullptr, 16384, 256,
      512);

  // Stem stage 1: 8 MLP blocks, dim 256, hidden 768.
  // LN for block 0 standalone; LN for blocks 1..7 fused into f2 (mgemm6).
  CONVH(s1_f1w, 8 * 196608, Wall);
  CONVH(s1_f2w, 8 * 196608, Wall + 1572864);
  lnC_kernel<256><<<16384 / 4, 256, 0, stream>>>(Xa, s1_n2w, s1_n2b, BufB);
  for (int i = 0; i < 8; ++i) {
    mgemm4_kernel<3, 128><<<(16384 / 128) * (768 / 128), 256, 0, stream>>>(
        BufB, Wall + i * 196608, s1_f1b + i * 768, nullptr, nullptr, BufC,
        nullptr, nullptr, 16384, 768, 256);
    if (i < 7) {
      mgemm6_kernel<<<16384 / 64, 256, 0, stream>>>(
          BufC, Wall + 1572864 + i * 196608, s1_f2b + i * 256, Xa, Xa, BufB,
          s1_n2w + (i + 1) * 256, s1_n2b + (i + 1) * 256, 16384, 768);
    } else {
      mgemm6_kernel<<<16384 / 64, 256, 0, stream>>>(
          BufC, Wall + 1572864 + i * 196608, s1_f2b + i * 256, Xa, Xa, nullptr,
          nullptr, nullptr, 16384, 768);
    }
  }
  // Merge 1 -> BufB [4096,1024] bf16 -> GEMM + pos -> Xa [4096,512]
  merge_ln_kernel<1><<<4096, 256, 0, stream>>>(Xa, m1_nw, m1_nb, BufB);
  CONVH(m1_rw, 524288, Wall);
  mgemm4_kernel<1, 64><<<(4096 / 64) * (512 / 128), 256, 0, stream>>>(
      BufB, Wall, nullptr, pos_embed, Xa, nullptr, nullptr, nullptr, 4096, 512,
      1024);

  // 20 main attention blocks. Per-layer weights at WallBig + l*3145728.
  for (int l = 0; l < 20; ++l) {
    ushort* Wl = WallBig + (size_t)l * 3145728;
    ln512_kernel<1><<<1024, 256, 0, stream>>>(Xa, mb_n1w + l * 512,
                                              mb_n1b + l * 512, nullptr, BufB);
    mgemm4_kernel<4, 64><<<(4096 / 64) * (1536 / 128), 256, 0, stream>>>(
        BufB, Wl, mb_qkvb + l * 1536, nullptr, nullptr, Qkvh, nullptr, nullptr,
        4096, 1536, 512);
    attn_fused2_kernel<<<512, 256, 0, stream>>>(Qkvh, mb_rpb + l * 7688, rpe,
                                                BufB);
    mgemm4_kernel<2, 64><<<(4096 / 64) * (512 / 128), 256, 0, stream>>>(
        BufB, Wl + 786432, mb_projb + l * 512, Xa, Xa, nullptr, nullptr,
        nullptr, 4096, 512, 512);
    ln512_kernel<1><<<1024, 256, 0, stream>>>(Xa, mb_n2w + l * 512,
                                              mb_n2b + l * 512, nullptr, BufB);
    mgemm4_kernel<3, 128><<<(4096 / 128) * (2048 / 128), 256, 0, stream>>>(
        BufB, Wl + 1048576, mb_f1b + l * 2048, nullptr, nullptr, F1h, nullptr,
        nullptr, 4096, 2048, 512);
    mgemm4_kernel<2, 64><<<(4096 / 64) * (512 / 128), 256, 0, stream>>>(
        F1h, Wl + 2097152, mb_f2b + l * 512, Xa, Xa, nullptr, nullptr, nullptr,
        4096, 512, 2048);
  }
  // Final LN -> d_out (f32)
  ln512_kernel<0><<<1024, 256, 0, stream>>>(Xa, fnorm_w, fnorm_b,
                                            (float*)d_out, nullptr);
}

// Round 23
// 3474.320 us; speedup vs baseline: 1.0249x; 1.0249x over previous
//
#include <hip/hip_runtime.h>
#include <math.h>

#define EPSV 1e-5f

typedef __attribute__((ext_vector_type(8))) short bf16x8;
typedef __attribute__((ext_vector_type(4))) float f32x4;
typedef unsigned short ushort;

__device__ inline ushort f2bf(float x) {
  unsigned u = __builtin_bit_cast(unsigned, x);
  u += 0x7FFFu + ((u >> 16) & 1u);
  return (ushort)(u >> 16);
}

// async global->LDS, 16 bytes per lane; dest = wave-uniform base + lane*16
#define GLOAD16(lptr, gptr)                                              \
  __builtin_amdgcn_global_load_lds(                                      \
      (const __attribute__((address_space(1))) unsigned int*)(gptr),     \
      (__attribute__((address_space(3))) unsigned int*)(lptr), 16, 0, 0)

// ---------------------------------------------------------------------------
// f32 -> bf16 plane conversion (contiguous). n4 = count/4.
// ---------------------------------------------------------------------------
__global__ __launch_bounds__(256) void convh_kernel(
    const float* __restrict__ in, ushort* __restrict__ hi, int n4) {
  int i = blockIdx.x * 256 + threadIdx.x;
  if (i >= n4) return;
  float4 v = ((const float4*)in)[i];
  float vv[4] = {v.x, v.y, v.z, v.w};
  unsigned hw[4];
#pragma unroll
  for (int e = 0; e < 4; ++e) hw[e] = f2bf(vv[e]);
  ((uint2*)hi)[i] = make_uint2(hw[0] | (hw[1] << 16), hw[2] | (hw[3] << 16));
}

// ---------------------------------------------------------------------------
// f32 -> bf16 for all 20 main layers of one weight type, strided dst.
// ---------------------------------------------------------------------------
__global__ __launch_bounds__(256) void convmain_kernel(
    const float* __restrict__ src, ushort* __restrict__ dst, int perLayer4,
    int dstOff4, int n4) {
  int i = blockIdx.x * 256 + threadIdx.x;
  if (i >= n4) return;
  int l = i / perLayer4;
  int r = i - l * perLayer4;
  float4 v = ((const float4*)src)[i];
  float vv[4] = {v.x, v.y, v.z, v.w};
  unsigned hw[4];
#pragma unroll
  for (int e = 0; e < 4; ++e) hw[e] = f2bf(vv[e]);
  ((uint2*)dst)[(size_t)l * 786432 + dstOff4 + r] =
      make_uint2(hw[0] | (hw[1] << 16), hw[2] | (hw[3] << 16));
}

// ---------------------------------------------------------------------------
// Patch embed + pnorm LN v2. Block = (b, n): 16 tokens x 128 ch, 256 thr.
// ---------------------------------------------------------------------------
__global__ __launch_bounds__(256) void patch_ln2_kernel(
    const float* __restrict__ x, const float* __restrict__ pw,
    const float* __restrict__ pbias, const float* __restrict__ nw,
    const float* __restrict__ nb, float* __restrict__ out) {
  int bid = blockIdx.x;  // b*256 + n
  int b = bid >> 8, n = bid & 255;
  int py = (n >> 4) * 16, px0 = (n & 15) * 16;
  __shared__ float xin[3][16][16];
  __shared__ float wls[128][52];
  __shared__ float pbs[128];
  int tid = threadIdx.x;
  if (tid < 192) {
    int ci = tid / 64, rr = (tid % 64) >> 2, c4 = tid & 3;
    const float* src =
        x + ((size_t)(b * 3 + ci) * 256 + (py + rr)) * 256 + px0 + c4 * 4;
    *(float4*)&xin[ci][rr][c4 * 4] = *(const float4*)src;
  }
  for (int idx = tid; idx < 6144; idx += 256) {
    int c = idx / 48, q = idx % 48;
    wls[c][q] = pw[c * 48 + q];
  }
  if (tid < 128) pbs[tid] = pbias[tid];
  __syncthreads();

  int tt = tid >> 4, cg = tid & 15;
  int ii = tt >> 2, jj = tt & 3;
  float xv[48];
#pragma unroll
  for (int ci = 0; ci < 3; ++ci)
#pragma unroll
    for (int dy = 0; dy < 4; ++dy)
#pragma unroll
      for (int dx = 0; dx < 4; ++dx)
        xv[ci * 16 + dy * 4 + dx] = xin[ci][ii * 4 + dy][jj * 4 + dx];

  float o[8];
#pragma unroll
  for (int e = 0; e < 8; ++e) {
    int c = cg + e * 16;
    float a = pbs[c];
#pragma unroll
    for (int q4 = 0; q4 < 12; ++q4) {
      float4 w4 = *(const float4*)&wls[c][q4 * 4];
      a += w4.x * xv[q4 * 4] + w4.y * xv[q4 * 4 + 1] + w4.z * xv[q4 * 4 + 2] +
           w4.w * xv[q4 * 4 + 3];
    }
    o[e] = a;
  }
  float s = 0.f;
#pragma unroll
  for (int e = 0; e < 8; ++e) s += o[e];
#pragma unroll
  for (int off = 8; off > 0; off >>= 1) s += __shfl_xor(s, off, 16);
  float mean = s * (1.0f / 128.0f);
  float sq = 0.f;
#pragma unroll
  for (int e = 0; e < 8; ++e) {
    float d = o[e] - mean;
    sq += d * d;
  }
#pragma unroll
  for (int off = 8; off > 0; off >>= 1) sq += __shfl_xor(sq, off, 16);
  float rstd = rsqrtf(sq * (1.0f / 128.0f) + EPSV);
  size_t base = ((size_t)bid * 16 + tt) * 128;
#pragma unroll
  for (int e = 0; e < 8; ++e) {
    int c = cg + e * 16;
    out[base + c] = (o[e] - mean) * rstd * nw[c] + nb[c];
  }
}

// ---------------------------------------------------------------------------
// LayerNorm over C (128/256), one wave per row, 4 rows/block -> bf16 plane.
// ---------------------------------------------------------------------------
template <int C>
__global__ __launch_bounds__(256) void lnC_kernel(
    const float* __restrict__ X, const float* __restrict__ w,
    const float* __restrict__ bb, ushort* __restrict__ outH) {
  constexpr int NV = C / 64;
  int wave = threadIdx.x >> 6, lane = threadIdx.x & 63;
  int row = blockIdx.x * 4 + wave;
  const float* xr = X + (size_t)row * C + lane * NV;
  float v[NV];
  if (NV == 2) {
    float2 t2 = *(const float2*)xr;
    v[0] = t2.x; v[1] = t2.y;
  } else {
#pragma unroll
    for (int q = 0; q < NV; q += 4) {
      float4 t4 = *(const float4*)(xr + q);
      v[q] = t4.x; v[q + 1] = t4.y; v[q + 2] = t4.z; v[q + 3] = t4.w;
    }
  }
  float s = 0.f;
#pragma unroll
  for (int q = 0; q < NV; ++q) s += v[q];
#pragma unroll
  for (int o = 32; o > 0; o >>= 1) s += __shfl_xor(s, o, 64);
  float mean = s * (1.0f / C);
  float sq = 0.f;
#pragma unroll
  for (int q = 0; q < NV; ++q) {
    float d = v[q] - mean;
    sq += d * d;
  }
#pragma unroll
  for (int o = 32; o > 0; o >>= 1) sq += __shfl_xor(sq, o, 64);
  float rstd = rsqrtf(sq * (1.0f / C) + EPSV);
#pragma unroll
  for (int q = 0; q < NV; ++q) {
    int c = lane * NV + q;
    outH[(size_t)row * C + c] = f2bf((v[q] - mean) * rstd * w[c] + bb[c]);
  }
}

// ---------------------------------------------------------------------------
// Patch merge gather + LN -> bf16 plane.
// ---------------------------------------------------------------------------
template <int MODE>
__global__ __launch_bounds__(256) void merge_ln_kernel(
    const float* __restrict__ Xin, const float* __restrict__ nw,
    const float* __restrict__ nb, ushort* __restrict__ outH) {
  constexpr int CM = MODE ? 1024 : 512;
  constexpr int NE = CM / 256;
  int ot = blockIdx.x;
  int tid = threadIdx.x;
  __shared__ float redA[4];
  __shared__ float redB[4];

  float v[NE];
#pragma unroll
  for (int e = 0; e < NE; ++e) {
    int cp = tid + e * 256;
    if (MODE == 0) {
      int b = ot >> 10, r = ot & 1023;
      int n = r >> 2, di = (r >> 1) & 1, dj = r & 1;
      int q = cp >> 7, c = cp & 127;
      int i = 2 * di + (q & 1), j = 2 * dj + (q >> 1);
      v[e] = Xin[((b * 256 + n) * 16 + i * 4 + j) * 128 + c];
    } else {
      int b = ot >> 8, n = ot & 255;
      int q = cp >> 8, c = cp & 255;
      int di = q & 1, dj = q >> 1;
      v[e] = Xin[((b * 256 + n) * 4 + di * 2 + dj) * 256 + c];
    }
  }
  float s = 0.f;
#pragma unroll
  for (int e = 0; e < NE; ++e) s += v[e];
#pragma unroll
  for (int o = 32; o > 0; o >>= 1) s += __shfl_xor(s, o, 64);
  if ((tid & 63) == 0) redA[tid >> 6] = s;
  __syncthreads();
  float mean = (redA[0] + redA[1] + redA[2] + redA[3]) * (1.0f / CM);
  float sq = 0.f;
#pragma unroll
  for (int e = 0; e < NE; ++e) {
    float d = v[e] - mean;
    sq += d * d;
  }
#pragma unroll
  for (int o = 32; o > 0; o >>= 1) sq += __shfl_xor(sq, o, 64);
  if ((tid & 63) == 0) redB[tid >> 6] = sq;
  __syncthreads();
  float var = (redB[0] + redB[1] + redB[2] + redB[3]) * (1.0f / CM);
  float rstd = rsqrtf(var + EPSV);
#pragma unroll
  for (int e = 0; e < NE; ++e) {
    int cp = tid + e * 256;
    outH[(size_t)ot * CM + cp] = f2bf((v[e] - mean) * rstd * nw[cp] + nb[cp]);
  }
}

// ---------------------------------------------------------------------------
// bf16 MFMA GEMM v5: BK=64, XOR-swizzled LDS, LDS-staged vectorized epilogue.
// EP 0: bias->f32. EP 1: +pos->f32. EP 2: +extra->f32 (residual).
// EP 3: gelu->bf16. EP 4: qkv->bf16 (Q cols x0.125).
// EP 5: residual->f32 AND fused next-block LN->bf16 (requires N==128, nb==1).
// ---------------------------------------------------------------------------
template <int EP, int BM>
__global__ __launch_bounds__(256) void mgemm4_kernel(
    const ushort* __restrict__ Ah, const ushort* __restrict__ Wh,
    const float* __restrict__ bias, const float* __restrict__ extra,
    float* __restrict__ outF, ushort* __restrict__ outH,
    const float* __restrict__ lnw, const float* __restrict__ lnb, int M, int N,
    int K) {
  constexpr int NI = BM / 32;
  constexpr int ASH = BM * 64;  // A tile shorts
  constexpr int LSZ = (ASH + 8192 > BM * 136) ? (ASH + 8192) : (BM * 136);
  __shared__ __align__(16) ushort Lds[LSZ];
  int nb = N >> 7;
  int bx = blockIdx.x % nb, by = blockIdx.x / nb;
  int tid = threadIdx.x;
  int wv = tid >> 6, lane = tid & 63;
  int srow = tid >> 3;
  int scol = ((tid & 7) ^ (srow & 7)) << 3;  // source-side swizzle (shorts)
  const ushort* aS = Ah + (size_t)(by * BM + srow) * K + scol;
  const ushort* wS = Wh + (size_t)(bx * 128 + srow) * K + scol;
  ushort* dA = Lds + wv * 512;
  ushort* dW = Lds + ASH + wv * 512;

  int wm = (wv >> 1) * (BM / 2), wn = (wv & 1) * 64;
  int fr = lane & 15, fq = lane >> 4;
  int rsw = fr & 7;  // read-side swizzle key

  f32x4 acc[NI][4];
#pragma unroll
  for (int i = 0; i < NI; ++i)
#pragma unroll
    for (int j = 0; j < 4; ++j) acc[i][j] = {0.f, 0.f, 0.f, 0.f};

  for (int k0 = 0; k0 < K; k0 += 64) {
#pragma unroll
    for (int q = 0; q < BM / 32; ++q)
      GLOAD16(dA + q * 2048, aS + (size_t)q * 32 * K + k0);
#pragma unroll
    for (int q = 0; q < 4; ++q)
      GLOAD16(dW + q * 2048, wS + (size_t)q * 32 * K + k0);
    __syncthreads();

#pragma unroll
    for (int kh = 0; kh < 2; ++kh) {
      bf16x8 fa[NI], fb[4];
#pragma unroll
      for (int i = 0; i < NI; ++i) {
        int row = wm + i * 16 + fr;
        fa[i] = *(const bf16x8*)(Lds + row * 64 + ((((kh << 2) + fq) ^ rsw) << 3));
      }
#pragma unroll
      for (int j = 0; j < 4; ++j) {
        int row = wn + j * 16 + fr;
        fb[j] = *(const bf16x8*)(Lds + ASH + row * 64 +
                                 ((((kh << 2) + fq) ^ rsw) << 3));
      }
#pragma unroll
      for (int i = 0; i < NI; ++i)
#pragma unroll
        for (int j = 0; j < 4; ++j)
          acc[i][j] = __builtin_amdgcn_mfma_f32_16x16x32_bf16(fa[i], fb[j],
                                                              acc[i][j], 0, 0,
                                                              0);
    }
    __syncthreads();
  }

  int row0 = by * BM;
  int col0 = bx * 128;
  if (EP == 3 || EP == 4) {
    ushort* LdsO = Lds;
#pragma unroll
    for (int j = 0; j < 4; ++j) {
      int col = wn + j * 16 + fr;
      float bvv = bias ? bias[col0 + col] : 0.f;
      bool sc = (EP == 4) && (col0 + col < 512);
#pragma unroll
      for (int i = 0; i < NI; ++i) {
#pragma unroll
        for (int e = 0; e < 4; ++e) {
          int rl = wm + i * 16 + fq * 4 + e;
          float o = acc[i][j][e] + bvv;
          if (EP == 3)
            o = 0.5f * o * (1.0f + erff(o * 0.70710678118654752f));
          else if (sc)
            o *= 0.125f;
          LdsO[rl * 136 + col] = f2bf(o);
        }
      }
    }
    __syncthreads();
#pragma unroll
    for (int p = 0; p < BM / 16; ++p) {
      int ch = p * 256 + tid;
      int r = ch >> 4, cc = (ch & 15) * 8;
      *(uint4*)&outH[(size_t)(row0 + r) * N + col0 + cc] =
          *(const uint4*)&LdsO[r * 136 + cc];
    }
  } else {
    float* LdsF = (float*)Lds;
    int strip = wv >> 1;
#pragma unroll
    for (int i = 0; i < NI; ++i) {
#pragma unroll
      for (int j = 0; j < 4; ++j) {
        int col = wn + j * 16 + fr;
        float bvv = bias ? bias[col0 + col] : 0.f;
#pragma unroll
        for (int e = 0; e < 4; ++e)
          LdsF[(strip * 16 + fq * 4 + e) * 136 + col] = acc[i][j][e] + bvv;
      }
      __syncthreads();
#pragma unroll
      for (int p = 0; p < 4; ++p) {
        int c = p * 256 + tid;  // 0..1023
        int st = c >> 9;
        int rem = c & 511;
        int r = rem >> 5, cc = (rem & 31) * 4;
        int grow = row0 + st * (BM / 2) + i * 16 + r;
        float4 v = *(const float4*)&LdsF[(st * 16 + r) * 136 + cc];
        if (EP == 1) {
          float4 e4 =
              *(const float4*)&extra[(size_t)(grow & 255) * N + col0 + cc];
          v.x += e4.x; v.y += e4.y; v.z += e4.z; v.w += e4.w;
        } else if (EP == 2 || EP == 5) {
          float4 e4 = *(const float4*)&extra[(size_t)grow * N + col0 + cc];
          v.x += e4.x; v.y += e4.y; v.z += e4.z; v.w += e4.w;
        }
        *(float4*)&outF[(size_t)grow * N + col0 + cc] = v;
        if (EP == 5) {
          // fused next-block LN (N==128, nb==1): each row's 128 cols live in
          // a 32-lane group (threads r*32..r*32+31 of this wave).
          float s1 = v.x + v.y + v.z + v.w;
#pragma unroll
          for (int o = 16; o > 0; o >>= 1) s1 += __shfl_xor(s1, o, 32);
          float mean = s1 * (1.0f / 128.0f);
          float dx = v.x - mean, dy = v.y - mean, dz = v.z - mean,
                dw = v.w - mean;
          float s2 = dx * dx + dy * dy + dz * dz + dw * dw;
#pragma unroll
          for (int o = 16; o > 0; o >>= 1) s2 += __shfl_xor(s2, o, 32);
          float rstd = rsqrtf(s2 * (1.0f / 128.0f) + EPSV);
          unsigned h0 = f2bf(dx * rstd * lnw[cc] + lnb[cc]);
          unsigned h1 = f2bf(dy * rstd * lnw[cc + 1] + lnb[cc + 1]);
          unsigned h2 = f2bf(dz * rstd * lnw[cc + 2] + lnb[cc + 2]);
          unsigned h3 = f2bf(dw * rstd * lnw[cc + 3] + lnb[cc + 3]);
          *(uint2*)&outH[(size_t)grow * N + cc] =
              make_uint2(h0 | (h1 << 16), h2 | (h3 << 16));
        }
      }
      __syncthreads();
    }
  }
}

// ---------------------------------------------------------------------------
// Fused MFMA attention: scores + softmax + PV in one kernel.
// Block = (b, h, 64 q-rows), grid 512, 256 thr. LDS ~77 KB -> 2 blocks/CU.
// ---------------------------------------------------------------------------
__global__ __launch_bounds__(256) void attn_fused2_kernel(
    const ushort* __restrict__ qkvh, const float* __restrict__ rpb,
    const int* __restrict__ rpe, ushort* __restrict__ outH) {
  int bid = blockIdx.x;
  int qc = bid & 3, bh = bid >> 2;
  int b = bh >> 3, h = bh & 7;
  int n0 = qc * 64;
  int tid = threadIdx.x;
  int wv = tid >> 6, lane = tid & 63;
  int fr = lane & 15, fq = lane >> 4;
  __shared__ __align__(16) ushort Qs[64 * 64];
  __shared__ __align__(16) ushort Ks[256 * 64];   // K, then P [64][256]
  __shared__ __align__(16) ushort Vt[64 * 256];
  __shared__ float rpbh[961];
  __shared__ float red[64][4];

  int srow = tid >> 3;
  int sc = ((tid & 7) ^ (srow & 7)) << 3;
  const ushort* Qg = qkvh + (size_t)(b * 256 + n0 + srow) * 1536 + h * 64 + sc;
  GLOAD16(Qs + wv * 512, Qg);
  GLOAD16(Qs + 2048 + wv * 512, Qg + (size_t)32 * 1536);
  const ushort* Kg = qkvh + (size_t)(b * 256 + srow) * 1536 + 512 + h * 64 + sc;
#pragma unroll
  for (int q = 0; q < 8; ++q)
    GLOAD16(Ks + q * 2048 + wv * 512, Kg + (size_t)q * 32 * 1536);
#pragma unroll
  for (int pass = 0; pass < 4; ++pass) {
    int m = pass * 64 + (tid >> 2);
    int sg = (tid & 3) * 16;
    const ushort* Vg = qkvh + (size_t)(b * 256 + m) * 1536 + 1024 + h * 64 + sg;
    ushort tmp[16];
    *(uint4*)tmp = *(const uint4*)Vg;
    *(uint4*)(tmp + 8) = *(const uint4*)(Vg + 8);
    int ch = m >> 3, ml = m & 7;
#pragma unroll
    for (int e = 0; e < 16; ++e) {
      int d = sg + e;
      int cs = (ch & 24) | ((ch & 7) ^ (d & 7));
      Vt[d * 256 + cs * 8 + ml] = tmp[e];
    }
  }
  for (int i = tid; i < 961; i += 256) rpbh[i] = rpb[i * 8 + h];
  __syncthreads();

  f32x4 acc[4][4];
#pragma unroll
  for (int i = 0; i < 4; ++i)
#pragma unroll
    for (int j = 0; j < 4; ++j) acc[i][j] = {0.f, 0.f, 0.f, 0.f};
#pragma unroll
  for (int kh = 0; kh < 2; ++kh) {
    bf16x8 fa[4], fb[4];
#pragma unroll
    for (int i = 0; i < 4; ++i) {
      int row = i * 16 + fr;
      fa[i] = *(const bf16x8*)(Qs + row * 64 +
                               ((((kh << 2) + fq) ^ (row & 7)) << 3));
    }
#pragma unroll
    for (int j = 0; j < 4; ++j) {
      int row = wv * 64 + j * 16 + fr;
      fb[j] = *(const bf16x8*)(Ks + row * 64 +
                               ((((kh << 2) + fq) ^ (row & 7)) << 3));
    }
#pragma unroll
    for (int i = 0; i < 4; ++i)
#pragma unroll
      for (int j = 0; j < 4; ++j)
        acc[i][j] = __builtin_amdgcn_mfma_f32_16x16x32_bf16(fa[i], fb[j],
                                                            acc[i][j], 0, 0, 0);
  }

  float sreg[4][4][4];  // [i][j][e]
#pragma unroll
  for (int i = 0; i < 4; ++i)
#pragma unroll
    for (int e = 0; e < 4; ++e) {
      int n = n0 + i * 16 + fq * 4 + e;
#pragma unroll
      for (int j = 0; j < 4; ++j) {
        int m = wv * 64 + j * 16 + fr;
        sreg[i][j][e] = acc[i][j][e] + rpbh[rpe[n * 256 + m]];
      }
    }

  float rmax[4][4];
#pragma unroll
  for (int i = 0; i < 4; ++i)
#pragma unroll
    for (int e = 0; e < 4; ++e) {
      float mx = fmaxf(fmaxf(sreg[i][0][e], sreg[i][1][e]),
                       fmaxf(sreg[i][2][e], sreg[i][3][e]));
#pragma unroll
      for (int o = 8; o > 0; o >>= 1) mx = fmaxf(mx, __shfl_xor(mx, o, 16));
      if (fr == 0) red[i * 16 + fq * 4 + e][wv] = mx;
    }
  __syncthreads();  // also: all K reads complete beyond this point
#pragma unroll
  for (int i = 0; i < 4; ++i)
#pragma unroll
    for (int e = 0; e < 4; ++e) {
      int row = i * 16 + fq * 4 + e;
      rmax[i][e] = fmaxf(fmaxf(red[row][0], red[row][1]),
                         fmaxf(red[row][2], red[row][3]));
    }
  __syncthreads();
  float rinv[4][4];
#pragma unroll
  for (int i = 0; i < 4; ++i)
#pragma unroll
    for (int e = 0; e < 4; ++e) {
      float sm = 0.f;
#pragma unroll
      for (int j = 0; j < 4; ++j) {
        sreg[i][j][e] = expf(sreg[i][j][e] - rmax[i][e]);
        sm += sreg[i][j][e];
      }
#pragma unroll
      for (int o = 8; o > 0; o >>= 1) sm += __shfl_xor(sm, o, 16);
      if (fr == 0) red[i * 16 + fq * 4 + e][wv] = sm;
    }
  __syncthreads();
#pragma unroll
  for (int i = 0; i < 4; ++i)
#pragma unroll
    for (int e = 0; e < 4; ++e) {
      int row = i * 16 + fq * 4 + e;
      rinv[i][e] =
          1.0f / (red[row][0] + red[row][1] + red[row][2] + red[row][3]);
    }
  ushort* Ps = Ks;
#pragma unroll
  for (int i = 0; i < 4; ++i)
#pragma unroll
    for (int e = 0; e < 4; ++e) {
      int qrow = i * 16 + fq * 4 + e;
#pragma unroll
      for (int j = 0; j < 4; ++j) {
        int m = wv * 64 + j * 16 + fr;
        int ch = m >> 3, t = m & 7;
        int cs = (ch & 24) | ((ch & 7) ^ (qrow & 7));
        Ps[qrow * 256 + cs * 8 + t] = f2bf(sreg[i][j][e] * rinv[i][e]);
      }
    }
  __syncthreads();

  f32x4 pacc[4];
#pragma unroll
  for (int i = 0; i < 4; ++i) pacc[i] = {0.f, 0.f, 0.f, 0.f};
  int dbase = wv * 16;
#pragma unroll
  for (int ks = 0; ks < 8; ++ks) {
    int ch = (ks << 2) + fq;
    bf16x8 fb;
    {
      int row = dbase + fr;
      int cs = (ch & 24) | ((ch & 7) ^ (row & 7));
      fb = *(const bf16x8*)(Vt + row * 256 + cs * 8);
    }
    bf16x8 fa[4];
#pragma unroll
    for (int i = 0; i < 4; ++i) {
      int row = i * 16 + fr;
      int cs = (ch & 24) | ((ch & 7) ^ (row & 7));
      fa[i] = *(const bf16x8*)(Ps + row * 256 + cs * 8);
    }
#pragma unroll
    for (int i = 0; i < 4; ++i)
      pacc[i] = __builtin_amdgcn_mfma_f32_16x16x32_bf16(fa[i], fb, pacc[i], 0,
                                                        0, 0);
  }
#pragma unroll
  for (int i = 0; i < 4; ++i)
#pragma unroll
    for (int e = 0; e < 4; ++e) {
      int q = i * 16 + fq * 4 + e;
      outH[(size_t)(b * 256 + n0 + q) * 512 + h * 64 + dbase + fr] =
          f2bf(pacc[i][e]);
    }
}

// ---------------------------------------------------------------------------
// LayerNorm over 512, wave per row, 4 rows/block. HL=0 f32, HL=1 bf16 plane.
// ---------------------------------------------------------------------------
template <int HL>
__global__ __launch_bounds__(256) void ln512_kernel(
    const float* __restrict__ X, const float* __restrict__ w,
    const float* __restrict__ bb, float* __restrict__ outF,
    ushort* __restrict__ outH) {
  int row = blockIdx.x * 4 + (threadIdx.x >> 6);
  int t = threadIdx.x & 63;
  const float4* xr = (const float4*)(X + (size_t)row * 512);
  float4 v0 = xr[t * 2], v1 = xr[t * 2 + 1];
  float s = v0.x + v0.y + v0.z + v0.w + v1.x + v1.y + v1.z + v1.w;
#pragma unroll
  for (int o = 32; o > 0; o >>= 1) s += __shfl_xor(s, o, 64);
  float mean = s * (1.0f / 512.0f);
  float dv[8] = {v0.x - mean, v0.y - mean, v0.z - mean, v0.w - mean,
                 v1.x - mean, v1.y - mean, v1.z - mean, v1.w - mean};
  float sq = 0.f;
#pragma unroll
  for (int e = 0; e < 8; ++e) sq += dv[e] * dv[e];
#pragma unroll
  for (int o = 32; o > 0; o >>= 1) sq += __shfl_xor(sq, o, 64);
  float rstd = rsqrtf(sq * (1.0f / 512.0f) + EPSV);
  int c = t * 8;
  float ov[8];
#pragma unroll
  for (int e = 0; e < 8; ++e) ov[e] = dv[e] * rstd * w[c + e] + bb[c + e];
  if (HL == 0) {
    float4 o0 = {ov[0], ov[1], ov[2], ov[3]};
    float4 o1 = {ov[4], ov[5], ov[6], ov[7]};
    ((float4*)(outF + (size_t)row * 512))[t * 2] = o0;
    ((float4*)(outF + (size_t)row * 512))[t * 2 + 1] = o1;
  } else {
    __align__(16) ushort h8[8];
#pragma unroll
    for (int e = 0; e < 8; ++e) h8[e] = f2bf(ov[e]);
    *(bf16x8*)(outH + (size_t)row * 512 + c) = *(bf16x8*)h8;
  }
}

// ---------------------------------------------------------------------------
extern "C" void kernel_launch(void* const* d_in, const int* in_sizes, int n_in,
                              void* d_out, int out_size, void* d_ws,
                              size_t ws_size, hipStream_t stream) {
  const float* x = (const float*)d_in[0];
  const float* patch_w = (const float*)d_in[1];
  const float* patch_b = (const float*)d_in[2];
  const float* pnorm_w = (const float*)d_in[3];
  const float* pnorm_b = (const float*)d_in[4];
  const float* s0_n2w = (const float*)d_in[5];
  const float* s0_n2b = (const float*)d_in[6];
  const float* s0_f1w = (const float*)d_in[7];
  const float* s0_f1b = (const float*)d_in[8];
  const float* s0_f2w = (const float*)d_in[9];
  const float* s0_f2b = (const float*)d_in[10];
  const float* m0_nw = (const float*)d_in[11];
  const float* m0_nb = (const float*)d_in[12];
  const float* m0_rw = (const float*)d_in[13];
  const float* s1_n2w = (const float*)d_in[14];
  const float* s1_n2b = (const float*)d_in[15];
  const float* s1_f1w = (const float*)d_in[16];
  const float* s1_f1b = (const float*)d_in[17];
  const float* s1_f2w = (const float*)d_in[18];
  const float* s1_f2b = (const float*)d_in[19];
  const float* m1_nw = (const float*)d_in[20];
  const float* m1_nb = (const float*)d_in[21];
  const float* m1_rw = (const float*)d_in[22];
  const float* pos_embed = (const float*)d_in[23];
  const float* mb_n1w = (const float*)d_in[24];
  const float* mb_n1b = (const float*)d_in[25];
  const float* mb_qkvw = (const float*)d_in[26];
  const float* mb_qkvb = (const float*)d_in[27];
  const float* mb_rpb = (const float*)d_in[28];
  const float* mb_projw = (const float*)d_in[29];
  const float* mb_projb = (const float*)d_in[30];
  const float* mb_n2w = (const float*)d_in[31];
  const float* mb_n2b = (const float*)d_in[32];
  const float* mb_f1w = (const float*)d_in[33];
  const float* mb_f1b = (const float*)d_in[34];
  const float* mb_f2w = (const float*)d_in[35];
  const float* mb_f2b = (const float*)d_in[36];
  const float* fnorm_w = (const float*)d_in[37];
  const float* fnorm_b = (const float*)d_in[38];
  const int* rpe = (const int*)d_in[39];

  // Workspace (235 MB of ~320 MiB):
  float* Xa = (float*)d_ws;
  ushort* BufB = (ushort*)(Xa + 8388608);
  ushort* BufC = (ushort*)(Xa + 12582912);
  ushort* Qkvh = BufC;
  ushort* F1h = BufC + 14680064;
  ushort* Wall = (ushort*)(Xa + 25165824);
  ushort* WallBig = (ushort*)(Xa + 27262976);

#define CONVH(src, cnt, dh)                                              \
  convh_kernel<<<((cnt) / 4 + 255) / 256, 256, 0, stream>>>(src, dh, (cnt) / 4)

  // Pre-convert ALL 20 main layers' weights (one pass per weight type).
  convmain_kernel<<<(20 * 196608 + 255) / 256, 256, 0, stream>>>(
      mb_qkvw, WallBig, 196608, 0, 20 * 196608);
  convmain_kernel<<<(20 * 65536 + 255) / 256, 256, 0, stream>>>(
      mb_projw, WallBig, 65536, 196608, 20 * 65536);
  convmain_kernel<<<(20 * 262144 + 255) / 256, 256, 0, stream>>>(
      mb_f1w, WallBig, 262144, 262144, 20 * 262144);
  convmain_kernel<<<(20 * 262144 + 255) / 256, 256, 0, stream>>>(
      mb_f2w, WallBig, 262144, 524288, 20 * 262144);

  // Patch embed + pnorm LN -> Xa [65536,128]
  patch_ln2_kernel<<<4096, 256, 0, stream>>>(x, patch_w, patch_b, pnorm_w,
                                             pnorm_b, Xa);

  // Stem stage 0: 8 MLP blocks, dim 128, hidden 384.
  // LN for block 0 standalone; LN for blocks 1..7 fused into f2 EP5.
  CONVH(s0_f1w, 8 * 49152, Wall);
  CONVH(s0_f2w, 8 * 49152, Wall + 393216);
  lnC_kernel<128><<<65536 / 4, 256, 0, stream>>>(Xa, s0_n2w, s0_n2b, BufB);
  for (int i = 0; i < 8; ++i) {
    mgemm4_kernel<3, 128><<<(65536 / 128) * (384 / 128), 256, 0, stream>>>(
        BufB, Wall + i * 49152, s0_f1b + i * 384, nullptr, nullptr, BufC,
        nullptr, nullptr, 65536, 384, 128);
    if (i < 7) {
      mgemm4_kernel<5, 64><<<(65536 / 64) * (128 / 128), 256, 0, stream>>>(
          BufC, Wall + 393216 + i * 49152, s0_f2b + i * 128, Xa, Xa, BufB,
          s0_n2w + (i + 1) * 128, s0_n2b + (i + 1) * 128, 65536, 128, 384);
    } else {
      mgemm4_kernel<2, 64><<<(65536 / 64) * (128 / 128), 256, 0, stream>>>(
          BufC, Wall + 393216 + i * 49152, s0_f2b + i * 128, Xa, Xa, nullptr,
          nullptr, nullptr, 65536, 128, 384);
    }
  }
  // Merge 0 -> BufB [16384,512] bf16 -> GEMM -> Xa [16384,256]
  merge_ln_kernel<0><<<16384, 256, 0, stream>>>(Xa, m0_nw, m0_nb, BufB);
  CONVH(m0_rw, 131072, Wall);
  mgemm4_kernel<0, 128><<<(16384 / 128) * (256 / 128), 256, 0, stream>>>(
      BufB, Wall, nullptr, nullptr, Xa, nullptr, nullptr, nullptr, 16384, 256,
      512);

  // Stem stage 1: 8 MLP blocks, dim 256, hidden 768
  CONVH(s1_f1w, 8 * 196608, Wall);
  CONVH(s1_f2w, 8 * 196608, Wall + 1572864);
  for (int i = 0; i < 8; ++i) {
    lnC_kernel<256><<<16384 / 4, 256, 0, stream>>>(Xa, s1_n2w + i * 256,
                                                   s1_n2b + i * 256, BufB);
    mgemm4_kernel<3, 128><<<(16384 / 128) * (768 / 128), 256, 0, stream>>>(
        BufB, Wall + i * 196608, s1_f1b + i * 768, nullptr, nullptr, BufC,
        nullptr, nullptr, 16384, 768, 256);
    mgemm4_kernel<2, 64><<<(16384 / 64) * (256 / 128), 256, 0, stream>>>(
        BufC, Wall + 1572864 + i * 196608, s1_f2b + i * 256, Xa, Xa, nullptr,
        nullptr, nullptr, 16384, 256, 768);
  }
  // Merge 1 -> BufB [4096,1024] bf16 -> GEMM + pos -> Xa [4096,512]
  merge_ln_kernel<1><<<4096, 256, 0, stream>>>(Xa, m1_nw, m1_nb, BufB);
  CONVH(m1_rw, 524288, Wall);
  mgemm4_kernel<1, 64><<<(4096 / 64) * (512 / 128), 256, 0, stream>>>(
      BufB, Wall, nullptr, pos_embed, Xa, nullptr, nullptr, nullptr, 4096, 512,
      1024);

  // 20 main attention blocks. Per-layer weights at WallBig + l*3145728.
  for (int l = 0; l < 20; ++l) {
    ushort* Wl = WallBig + (size_t)l * 3145728;
    ln512_kernel<1><<<1024, 256, 0, stream>>>(Xa, mb_n1w + l * 512,
                                              mb_n1b + l * 512, nullptr, BufB);
    mgemm4_kernel<4, 64><<<(4096 / 64) * (1536 / 128), 256, 0, stream>>>(
        BufB, Wl, mb_qkvb + l * 1536, nullptr, nullptr, Qkvh, nullptr, nullptr,
        4096, 1536, 512);
    attn_fused2_kernel<<<512, 256, 0, stream>>>(Qkvh, mb_rpb + l * 7688, rpe,
                                                BufB);
    mgemm4_kernel<2, 64><<<(4096 / 64) * (512 / 128), 256, 0, stream>>>(
        BufB, Wl + 786432, mb_projb + l * 512, Xa, Xa, nullptr, nullptr,
        nullptr, 4096, 512, 512);
    ln512_kernel<1><<<1024, 256, 0, stream>>>(Xa, mb_n2w + l * 512,
                                              mb_n2b + l * 512, nullptr, BufB);
    mgemm4_kernel<3, 128><<<(4096 / 128) * (2048 / 128), 256, 0, stream>>>(
        BufB, Wl + 1048576, mb_f1b + l * 2048, nullptr, nullptr, F1h, nullptr,
        nullptr, 4096, 2048, 512);
    mgemm4_kernel<2, 64><<<(4096 / 64) * (512 / 128), 256, 0, stream>>>(
        F1h, Wl + 2097152, mb_f2b + l * 512, Xa, Xa, nullptr, nullptr, nullptr,
        4096, 512, 2048);
  }
  // Final LN -> d_out (f32)
  ln512_kernel<0><<<1024, 256, 0, stream>>>(Xa, fnorm_w, fnorm_b,
                                            (float*)d_out, nullptr);
}

// Round 24
// 3263.850 us; speedup vs baseline: 1.0910x; 1.0645x over previous
//
#include <hip/hip_runtime.h>
#include <math.h>

#define EPSV 1e-5f

typedef __attribute__((ext_vector_type(8))) short bf16x8;
typedef __attribute__((ext_vector_type(4))) float f32x4;
typedef unsigned short ushort;

__device__ inline ushort f2bf(float x) {
  unsigned u = __builtin_bit_cast(unsigned, x);
  u += 0x7FFFu + ((u >> 16) & 1u);
  return (ushort)(u >> 16);
}

// async global->LDS, 16 bytes per lane; dest = wave-uniform base + lane*16
#define GLOAD16(lptr, gptr)                                              \
  __builtin_amdgcn_global_load_lds(                                      \
      (const __attribute__((address_space(1))) unsigned int*)(gptr),     \
      (__attribute__((address_space(3))) unsigned int*)(lptr), 16, 0, 0)

// ---------------------------------------------------------------------------
// f32 -> bf16 plane conversion (contiguous). n4 = count/4.
// ---------------------------------------------------------------------------
__global__ __launch_bounds__(256) void convh_kernel(
    const float* __restrict__ in, ushort* __restrict__ hi, int n4) {
  int i = blockIdx.x * 256 + threadIdx.x;
  if (i >= n4) return;
  float4 v = ((const float4*)in)[i];
  float vv[4] = {v.x, v.y, v.z, v.w};
  unsigned hw[4];
#pragma unroll
  for (int e = 0; e < 4; ++e) hw[e] = f2bf(vv[e]);
  ((uint2*)hi)[i] = make_uint2(hw[0] | (hw[1] << 16), hw[2] | (hw[3] << 16));
}

// ---------------------------------------------------------------------------
// f32 -> bf16 for all 20 main layers of one weight type, strided dst.
// ---------------------------------------------------------------------------
__global__ __launch_bounds__(256) void convmain_kernel(
    const float* __restrict__ src, ushort* __restrict__ dst, int perLayer4,
    int dstOff4, int n4) {
  int i = blockIdx.x * 256 + threadIdx.x;
  if (i >= n4) return;
  int l = i / perLayer4;
  int r = i - l * perLayer4;
  float4 v = ((const float4*)src)[i];
  float vv[4] = {v.x, v.y, v.z, v.w};
  unsigned hw[4];
#pragma unroll
  for (int e = 0; e < 4; ++e) hw[e] = f2bf(vv[e]);
  ((uint2*)dst)[(size_t)l * 786432 + dstOff4 + r] =
      make_uint2(hw[0] | (hw[1] << 16), hw[2] | (hw[3] << 16));
}

// ---------------------------------------------------------------------------
// Patch embed + pnorm LN v2. Block = (b, n): 16 tokens x 128 ch, 256 thr.
// ---------------------------------------------------------------------------
__global__ __launch_bounds__(256) void patch_ln2_kernel(
    const float* __restrict__ x, const float* __restrict__ pw,
    const float* __restrict__ pbias, const float* __restrict__ nw,
    const float* __restrict__ nb, float* __restrict__ out) {
  int bid = blockIdx.x;  // b*256 + n
  int b = bid >> 8, n = bid & 255;
  int py = (n >> 4) * 16, px0 = (n & 15) * 16;
  __shared__ float xin[3][16][16];
  __shared__ float wls[128][52];
  __shared__ float pbs[128];
  int tid = threadIdx.x;
  if (tid < 192) {
    int ci = tid / 64, rr = (tid % 64) >> 2, c4 = tid & 3;
    const float* src =
        x + ((size_t)(b * 3 + ci) * 256 + (py + rr)) * 256 + px0 + c4 * 4;
    *(float4*)&xin[ci][rr][c4 * 4] = *(const float4*)src;
  }
  for (int idx = tid; idx < 6144; idx += 256) {
    int c = idx / 48, q = idx % 48;
    wls[c][q] = pw[c * 48 + q];
  }
  if (tid < 128) pbs[tid] = pbias[tid];
  __syncthreads();

  int tt = tid >> 4, cg = tid & 15;
  int ii = tt >> 2, jj = tt & 3;
  float xv[48];
#pragma unroll
  for (int ci = 0; ci < 3; ++ci)
#pragma unroll
    for (int dy = 0; dy < 4; ++dy)
#pragma unroll
      for (int dx = 0; dx < 4; ++dx)
        xv[ci * 16 + dy * 4 + dx] = xin[ci][ii * 4 + dy][jj * 4 + dx];

  float o[8];
#pragma unroll
  for (int e = 0; e < 8; ++e) {
    int c = cg + e * 16;
    float a = pbs[c];
#pragma unroll
    for (int q4 = 0; q4 < 12; ++q4) {
      float4 w4 = *(const float4*)&wls[c][q4 * 4];
      a += w4.x * xv[q4 * 4] + w4.y * xv[q4 * 4 + 1] + w4.z * xv[q4 * 4 + 2] +
           w4.w * xv[q4 * 4 + 3];
    }
    o[e] = a;
  }
  float s = 0.f;
#pragma unroll
  for (int e = 0; e < 8; ++e) s += o[e];
#pragma unroll
  for (int off = 8; off > 0; off >>= 1) s += __shfl_xor(s, off, 16);
  float mean = s * (1.0f / 128.0f);
  float sq = 0.f;
#pragma unroll
  for (int e = 0; e < 8; ++e) {
    float d = o[e] - mean;
    sq += d * d;
  }
#pragma unroll
  for (int off = 8; off > 0; off >>= 1) sq += __shfl_xor(sq, off, 16);
  float rstd = rsqrtf(sq * (1.0f / 128.0f) + EPSV);
  size_t base = ((size_t)bid * 16 + tt) * 128;
#pragma unroll
  for (int e = 0; e < 8; ++e) {
    int c = cg + e * 16;
    out[base + c] = (o[e] - mean) * rstd * nw[c] + nb[c];
  }
}

// ---------------------------------------------------------------------------
// LayerNorm over C (128/256), one wave per row, 4 rows/block -> bf16 plane.
// ---------------------------------------------------------------------------
template <int C>
__global__ __launch_bounds__(256) void lnC_kernel(
    const float* __restrict__ X, const float* __restrict__ w,
    const float* __restrict__ bb, ushort* __restrict__ outH) {
  constexpr int NV = C / 64;
  int wave = threadIdx.x >> 6, lane = threadIdx.x & 63;
  int row = blockIdx.x * 4 + wave;
  const float* xr = X + (size_t)row * C + lane * NV;
  float v[NV];
  if (NV == 2) {
    float2 t2 = *(const float2*)xr;
    v[0] = t2.x; v[1] = t2.y;
  } else {
#pragma unroll
    for (int q = 0; q < NV; q += 4) {
      float4 t4 = *(const float4*)(xr + q);
      v[q] = t4.x; v[q + 1] = t4.y; v[q + 2] = t4.z; v[q + 3] = t4.w;
    }
  }
  float s = 0.f;
#pragma unroll
  for (int q = 0; q < NV; ++q) s += v[q];
#pragma unroll
  for (int o = 32; o > 0; o >>= 1) s += __shfl_xor(s, o, 64);
  float mean = s * (1.0f / C);
  float sq = 0.f;
#pragma unroll
  for (int q = 0; q < NV; ++q) {
    float d = v[q] - mean;
    sq += d * d;
  }
#pragma unroll
  for (int o = 32; o > 0; o >>= 1) sq += __shfl_xor(sq, o, 64);
  float rstd = rsqrtf(sq * (1.0f / C) + EPSV);
#pragma unroll
  for (int q = 0; q < NV; ++q) {
    int c = lane * NV + q;
    outH[(size_t)row * C + c] = f2bf((v[q] - mean) * rstd * w[c] + bb[c]);
  }
}

// ---------------------------------------------------------------------------
// Patch merge gather + LN -> bf16 plane.
// ---------------------------------------------------------------------------
template <int MODE>
__global__ __launch_bounds__(256) void merge_ln_kernel(
    const float* __restrict__ Xin, const float* __restrict__ nw,
    const float* __restrict__ nb, ushort* __restrict__ outH) {
  constexpr int CM = MODE ? 1024 : 512;
  constexpr int NE = CM / 256;
  int ot = blockIdx.x;
  int tid = threadIdx.x;
  __shared__ float redA[4];
  __shared__ float redB[4];

  float v[NE];
#pragma unroll
  for (int e = 0; e < NE; ++e) {
    int cp = tid + e * 256;
    if (MODE == 0) {
      int b = ot >> 10, r = ot & 1023;
      int n = r >> 2, di = (r >> 1) & 1, dj = r & 1;
      int q = cp >> 7, c = cp & 127;
      int i = 2 * di + (q & 1), j = 2 * dj + (q >> 1);
      v[e] = Xin[((b * 256 + n) * 16 + i * 4 + j) * 128 + c];
    } else {
      int b = ot >> 8, n = ot & 255;
      int q = cp >> 8, c = cp & 255;
      int di = q & 1, dj = q >> 1;
      v[e] = Xin[((b * 256 + n) * 4 + di * 2 + dj) * 256 + c];
    }
  }
  float s = 0.f;
#pragma unroll
  for (int e = 0; e < NE; ++e) s += v[e];
#pragma unroll
  for (int o = 32; o > 0; o >>= 1) s += __shfl_xor(s, o, 64);
  if ((tid & 63) == 0) redA[tid >> 6] = s;
  __syncthreads();
  float mean = (redA[0] + redA[1] + redA[2] + redA[3]) * (1.0f / CM);
  float sq = 0.f;
#pragma unroll
  for (int e = 0; e < NE; ++e) {
    float d = v[e] - mean;
    sq += d * d;
  }
#pragma unroll
  for (int o = 32; o > 0; o >>= 1) sq += __shfl_xor(sq, o, 64);
  if ((tid & 63) == 0) redB[tid >> 6] = sq;
  __syncthreads();
  float var = (redB[0] + redB[1] + redB[2] + redB[3]) * (1.0f / CM);
  float rstd = rsqrtf(var + EPSV);
#pragma unroll
  for (int e = 0; e < NE; ++e) {
    int cp = tid + e * 256;
    outH[(size_t)ot * CM + cp] = f2bf((v[e] - mean) * rstd * nw[cp] + nb[cp]);
  }
}

// ---------------------------------------------------------------------------
// bf16 MFMA GEMM v5: BK=64, XOR-swizzled LDS, LDS-staged vectorized epilogue.
// EP 0: bias->f32. EP 1: +pos->f32. EP 2: +extra->f32 (residual).
// EP 3: gelu->bf16. EP 4: qkv->bf16 (Q cols x0.125).
// EP 5: residual->f32 AND fused next-block LN->bf16 (requires N==128, nb==1).
// BM in {32, 64, 128}.
// ---------------------------------------------------------------------------
template <int EP, int BM>
__global__ __launch_bounds__(256) void mgemm4_kernel(
    const ushort* __restrict__ Ah, const ushort* __restrict__ Wh,
    const float* __restrict__ bias, const float* __restrict__ extra,
    float* __restrict__ outF, ushort* __restrict__ outH,
    const float* __restrict__ lnw, const float* __restrict__ lnb, int M, int N,
    int K) {
  constexpr int NI = BM / 32;
  constexpr int ASH = BM * 64;  // A tile shorts
  constexpr int FSH = BM * 136 * 2 / ((BM == 32) ? 1 : 2);  // (unused helper)
  constexpr int LSZ =
      (ASH + 8192 > ((BM == 32) ? 32 * 136 * 2 : BM * 136))
          ? (ASH + 8192)
          : ((BM == 32) ? 32 * 136 * 2 : BM * 136);
  __shared__ __align__(16) ushort Lds[LSZ];
  int nb = N >> 7;
  int bx = blockIdx.x % nb, by = blockIdx.x / nb;
  int tid = threadIdx.x;
  int wv = tid >> 6, lane = tid & 63;
  int srow = tid >> 3;
  int scol = ((tid & 7) ^ (srow & 7)) << 3;  // source-side swizzle (shorts)
  const ushort* aS = Ah + (size_t)(by * BM + srow) * K + scol;
  const ushort* wS = Wh + (size_t)(bx * 128 + srow) * K + scol;
  ushort* dA = Lds + wv * 512;
  ushort* dW = Lds + ASH + wv * 512;

  int wm = (wv >> 1) * (BM / 2), wn = (wv & 1) * 64;
  int fr = lane & 15, fq = lane >> 4;
  int rsw = fr & 7;  // read-side swizzle key

  f32x4 acc[NI][4];
#pragma unroll
  for (int i = 0; i < NI; ++i)
#pragma unroll
    for (int j = 0; j < 4; ++j) acc[i][j] = {0.f, 0.f, 0.f, 0.f};

  for (int k0 = 0; k0 < K; k0 += 64) {
#pragma unroll
    for (int q = 0; q < (BM + 31) / 32; ++q)
      GLOAD16(dA + q * 2048, aS + (size_t)q * 32 * K + k0);
#pragma unroll
    for (int q = 0; q < 4; ++q)
      GLOAD16(dW + q * 2048, wS + (size_t)q * 32 * K + k0);
    __syncthreads();

#pragma unroll
    for (int kh = 0; kh < 2; ++kh) {
      bf16x8 fa[NI], fb[4];
#pragma unroll
      for (int i = 0; i < NI; ++i) {
        int row = wm + i * 16 + fr;
        fa[i] = *(const bf16x8*)(Lds + row * 64 + ((((kh << 2) + fq) ^ rsw) << 3));
      }
#pragma unroll
      for (int j = 0; j < 4; ++j) {
        int row = wn + j * 16 + fr;
        fb[j] = *(const bf16x8*)(Lds + ASH + row * 64 +
                                 ((((kh << 2) + fq) ^ rsw) << 3));
      }
#pragma unroll
      for (int i = 0; i < NI; ++i)
#pragma unroll
        for (int j = 0; j < 4; ++j)
          acc[i][j] = __builtin_amdgcn_mfma_f32_16x16x32_bf16(fa[i], fb[j],
                                                              acc[i][j], 0, 0,
                                                              0);
    }
    __syncthreads();
  }

  int row0 = by * BM;
  int col0 = bx * 128;
  if (EP == 3 || EP == 4) {
    ushort* LdsO = Lds;
#pragma unroll
    for (int j = 0; j < 4; ++j) {
      int col = wn + j * 16 + fr;
      float bvv = bias ? bias[col0 + col] : 0.f;
      bool sc = (EP == 4) && (col0 + col < 512);
#pragma unroll
      for (int i = 0; i < NI; ++i) {
#pragma unroll
        for (int e = 0; e < 4; ++e) {
          int rl = wm + i * 16 + fq * 4 + e;
          float o = acc[i][j][e] + bvv;
          if (EP == 3)
            o = 0.5f * o * (1.0f + erff(o * 0.70710678118654752f));
          else if (sc)
            o *= 0.125f;
          LdsO[rl * 136 + col] = f2bf(o);
        }
      }
    }
    __syncthreads();
#pragma unroll
    for (int p = 0; p < BM / 16; ++p) {
      int ch = p * 256 + tid;
      int r = ch >> 4, cc = (ch & 15) * 8;
      *(uint4*)&outH[(size_t)(row0 + r) * N + col0 + cc] =
          *(const uint4*)&LdsO[r * 136 + cc];
    }
  } else {
    float* LdsF = (float*)Lds;
    int strip = wv >> 1;
#pragma unroll
    for (int i = 0; i < NI; ++i) {
#pragma unroll
      for (int j = 0; j < 4; ++j) {
        int col = wn + j * 16 + fr;
        float bvv = bias ? bias[col0 + col] : 0.f;
#pragma unroll
        for (int e = 0; e < 4; ++e)
          LdsF[(strip * 16 + fq * 4 + e) * 136 + col] = acc[i][j][e] + bvv;
      }
      __syncthreads();
#pragma unroll
      for (int p = 0; p < 4; ++p) {
        int c = p * 256 + tid;  // 0..1023
        int st = c >> 9;
        int rem = c & 511;
        int r = rem >> 5, cc = (rem & 31) * 4;
        int grow = row0 + st * (BM / 2) + i * 16 + r;
        float4 v = *(const float4*)&LdsF[(st * 16 + r) * 136 + cc];
        if (EP == 1) {
          float4 e4 =
              *(const float4*)&extra[(size_t)(grow & 255) * N + col0 + cc];
          v.x += e4.x; v.y += e4.y; v.z += e4.z; v.w += e4.w;
        } else if (EP == 2 || EP == 5) {
          float4 e4 = *(const float4*)&extra[(size_t)grow * N + col0 + cc];
          v.x += e4.x; v.y += e4.y; v.z += e4.z; v.w += e4.w;
        }
        *(float4*)&outF[(size_t)grow * N + col0 + cc] = v;
        if (EP == 5) {
          // fused next-block LN (N==128, nb==1): each row's 128 cols live in
          // a 32-lane group (threads r*32..r*32+31 of this wave).
          float s1 = v.x + v.y + v.z + v.w;
#pragma unroll
          for (int o = 16; o > 0; o >>= 1) s1 += __shfl_xor(s1, o, 32);
          float mean = s1 * (1.0f / 128.0f);
          float dx = v.x - mean, dy = v.y - mean, dz = v.z - mean,
                dw = v.w - mean;
          float s2 = dx * dx + dy * dy + dz * dz + dw * dw;
#pragma unroll
          for (int o = 16; o > 0; o >>= 1) s2 += __shfl_xor(s2, o, 32);
          float rstd = rsqrtf(s2 * (1.0f / 128.0f) + EPSV);
          unsigned h0 = f2bf(dx * rstd * lnw[cc] + lnb[cc]);
          unsigned h1 = f2bf(dy * rstd * lnw[cc + 1] + lnb[cc + 1]);
          unsigned h2 = f2bf(dz * rstd * lnw[cc + 2] + lnb[cc + 2]);
          unsigned h3 = f2bf(dw * rstd * lnw[cc + 3] + lnb[cc + 3]);
          *(uint2*)&outH[(size_t)grow * N + cc] =
              make_uint2(h0 | (h1 << 16), h2 | (h3 << 16));
        }
      }
      __syncthreads();
    }
  }
}

// ---------------------------------------------------------------------------
// Fused MFMA attention: scores + softmax + PV in one kernel.
// Block = (b, h, 64 q-rows), grid 512, 256 thr. LDS ~77 KB -> 2 blocks/CU.
// ---------------------------------------------------------------------------
__global__ __launch_bounds__(256) void attn_fused2_kernel(
    const ushort* __restrict__ qkvh, const float* __restrict__ rpb,
    const int* __restrict__ rpe, ushort* __restrict__ outH) {
  int bid = blockIdx.x;
  int qc = bid & 3, bh = bid >> 2;
  int b = bh >> 3, h = bh & 7;
  int n0 = qc * 64;
  int tid = threadIdx.x;
  int wv = tid >> 6, lane = tid & 63;
  int fr = lane & 15, fq = lane >> 4;
  __shared__ __align__(16) ushort Qs[64 * 64];
  __shared__ __align__(16) ushort Ks[256 * 64];   // K, then P [64][256]
  __shared__ __align__(16) ushort Vt[64 * 256];
  __shared__ float rpbh[961];
  __shared__ float red[64][4];

  int srow = tid >> 3;
  int sc = ((tid & 7) ^ (srow & 7)) << 3;
  const ushort* Qg = qkvh + (size_t)(b * 256 + n0 + srow) * 1536 + h * 64 + sc;
  GLOAD16(Qs + wv * 512, Qg);
  GLOAD16(Qs + 2048 + wv * 512, Qg + (size_t)32 * 1536);
  const ushort* Kg = qkvh + (size_t)(b * 256 + srow) * 1536 + 512 + h * 64 + sc;
#pragma unroll
  for (int q = 0; q < 8; ++q)
    GLOAD16(Ks + q * 2048 + wv * 512, Kg + (size_t)q * 32 * 1536);
#pragma unroll
  for (int pass = 0; pass < 4; ++pass) {
    int m = pass * 64 + (tid >> 2);
    int sg = (tid & 3) * 16;
    const ushort* Vg = qkvh + (size_t)(b * 256 + m) * 1536 + 1024 + h * 64 + sg;
    ushort tmp[16];
    *(uint4*)tmp = *(const uint4*)Vg;
    *(uint4*)(tmp + 8) = *(const uint4*)(Vg + 8);
    int ch = m >> 3, ml = m & 7;
#pragma unroll
    for (int e = 0; e < 16; ++e) {
      int d = sg + e;
      int cs = (ch & 24) | ((ch & 7) ^ (d & 7));
      Vt[d * 256 + cs * 8 + ml] = tmp[e];
    }
  }
  for (int i = tid; i < 961; i += 256) rpbh[i] = rpb[i * 8 + h];
  __syncthreads();

  f32x4 acc[4][4];
#pragma unroll
  for (int i = 0; i < 4; ++i)
#pragma unroll
    for (int j = 0; j < 4; ++j) acc[i][j] = {0.f, 0.f, 0.f, 0.f};
#pragma unroll
  for (int kh = 0; kh < 2; ++kh) {
    bf16x8 fa[4], fb[4];
#pragma unroll
    for (int i = 0; i < 4; ++i) {
      int row = i * 16 + fr;
      fa[i] = *(const bf16x8*)(Qs + row * 64 +
                               ((((kh << 2) + fq) ^ (row & 7)) << 3));
    }
#pragma unroll
    for (int j = 0; j < 4; ++j) {
      int row = wv * 64 + j * 16 + fr;
      fb[j] = *(const bf16x8*)(Ks + row * 64 +
                               ((((kh << 2) + fq) ^ (row & 7)) << 3));
    }
#pragma unroll
    for (int i = 0; i < 4; ++i)
#pragma unroll
      for (int j = 0; j < 4; ++j)
        acc[i][j] = __builtin_amdgcn_mfma_f32_16x16x32_bf16(fa[i], fb[j],
                                                            acc[i][j], 0, 0, 0);
  }

  float sreg[4][4][4];  // [i][j][e]
#pragma unroll
  for (int i = 0; i < 4; ++i)
#pragma unroll
    for (int e = 0; e < 4; ++e) {
      int n = n0 + i * 16 + fq * 4 + e;
#pragma unroll
      for (int j = 0; j < 4; ++j) {
        int m = wv * 64 + j * 16 + fr;
        sreg[i][j][e] = acc[i][j][e] + rpbh[rpe[n * 256 + m]];
      }
    }

  float rmax[4][4];
#pragma unroll
  for (int i = 0; i < 4; ++i)
#pragma unroll
    for (int e = 0; e < 4; ++e) {
      float mx = fmaxf(fmaxf(sreg[i][0][e], sreg[i][1][e]),
                       fmaxf(sreg[i][2][e], sreg[i][3][e]));
#pragma unroll
      for (int o = 8; o > 0; o >>= 1) mx = fmaxf(mx, __shfl_xor(mx, o, 16));
      if (fr == 0) red[i * 16 + fq * 4 + e][wv] = mx;
    }
  __syncthreads();  // also: all K reads complete beyond this point
#pragma unroll
  for (int i = 0; i < 4; ++i)
#pragma unroll
    for (int e = 0; e < 4; ++e) {
      int row = i * 16 + fq * 4 + e;
      rmax[i][e] = fmaxf(fmaxf(red[row][0], red[row][1]),
                         fmaxf(red[row][2], red[row][3]));
    }
  __syncthreads();
  float rinv[4][4];
#pragma unroll
  for (int i = 0; i < 4; ++i)
#pragma unroll
    for (int e = 0; e < 4; ++e) {
      float sm = 0.f;
#pragma unroll
      for (int j = 0; j < 4; ++j) {
        sreg[i][j][e] = expf(sreg[i][j][e] - rmax[i][e]);
        sm += sreg[i][j][e];
      }
#pragma unroll
      for (int o = 8; o > 0; o >>= 1) sm += __shfl_xor(sm, o, 16);
      if (fr == 0) red[i * 16 + fq * 4 + e][wv] = sm;
    }
  __syncthreads();
#pragma unroll
  for (int i = 0; i < 4; ++i)
#pragma unroll
    for (int e = 0; e < 4; ++e) {
      int row = i * 16 + fq * 4 + e;
      rinv[i][e] =
          1.0f / (red[row][0] + red[row][1] + red[row][2] + red[row][3]);
    }
  ushort* Ps = Ks;
#pragma unroll
  for (int i = 0; i < 4; ++i)
#pragma unroll
    for (int e = 0; e < 4; ++e) {
      int qrow = i * 16 + fq * 4 + e;
#pragma unroll
      for (int j = 0; j < 4; ++j) {
        int m = wv * 64 + j * 16 + fr;
        int ch = m >> 3, t = m & 7;
        int cs = (ch & 24) | ((ch & 7) ^ (qrow & 7));
        Ps[qrow * 256 + cs * 8 + t] = f2bf(sreg[i][j][e] * rinv[i][e]);
      }
    }
  __syncthreads();

  f32x4 pacc[4];
#pragma unroll
  for (int i = 0; i < 4; ++i) pacc[i] = {0.f, 0.f, 0.f, 0.f};
  int dbase = wv * 16;
#pragma unroll
  for (int ks = 0; ks < 8; ++ks) {
    int ch = (ks << 2) + fq;
    bf16x8 fb;
    {
      int row = dbase + fr;
      int cs = (ch & 24) | ((ch & 7) ^ (row & 7));
      fb = *(const bf16x8*)(Vt + row * 256 + cs * 8);
    }
    bf16x8 fa[4];
#pragma unroll
    for (int i = 0; i < 4; ++i) {
      int row = i * 16 + fr;
      int cs = (ch & 24) | ((ch & 7) ^ (row & 7));
      fa[i] = *(const bf16x8*)(Ps + row * 256 + cs * 8);
    }
#pragma unroll
    for (int i = 0; i < 4; ++i)
      pacc[i] = __builtin_amdgcn_mfma_f32_16x16x32_bf16(fa[i], fb, pacc[i], 0,
                                                        0, 0);
  }
#pragma unroll
  for (int i = 0; i < 4; ++i)
#pragma unroll
    for (int e = 0; e < 4; ++e) {
      int q = i * 16 + fq * 4 + e;
      outH[(size_t)(b * 256 + n0 + q) * 512 + h * 64 + dbase + fr] =
          f2bf(pacc[i][e]);
    }
}

// ---------------------------------------------------------------------------
// LayerNorm over 512, wave per row, 4 rows/block. HL=0 f32, HL=1 bf16 plane.
// ---------------------------------------------------------------------------
template <int HL>
__global__ __launch_bounds__(256) void ln512_kernel(
    const float* __restrict__ X, const float* __restrict__ w,
    const float* __restrict__ bb, float* __restrict__ outF,
    ushort* __restrict__ outH) {
  int row = blockIdx.x * 4 + (threadIdx.x >> 6);
  int t = threadIdx.x & 63;
  const float4* xr = (const float4*)(X + (size_t)row * 512);
  float4 v0 = xr[t * 2], v1 = xr[t * 2 + 1];
  float s = v0.x + v0.y + v0.z + v0.w + v1.x + v1.y + v1.z + v1.w;
#pragma unroll
  for (int o = 32; o > 0; o >>= 1) s += __shfl_xor(s, o, 64);
  float mean = s * (1.0f / 512.0f);
  float dv[8] = {v0.x - mean, v0.y - mean, v0.z - mean, v0.w - mean,
                 v1.x - mean, v1.y - mean, v1.z - mean, v1.w - mean};
  float sq = 0.f;
#pragma unroll
  for (int e = 0; e < 8; ++e) sq += dv[e] * dv[e];
#pragma unroll
  for (int o = 32; o > 0; o >>= 1) sq += __shfl_xor(sq, o, 64);
  float rstd = rsqrtf(sq * (1.0f / 512.0f) + EPSV);
  int c = t * 8;
  float ov[8];
#pragma unroll
  for (int e = 0; e < 8; ++e) ov[e] = dv[e] * rstd * w[c + e] + bb[c + e];
  if (HL == 0) {
    float4 o0 = {ov[0], ov[1], ov[2], ov[3]};
    float4 o1 = {ov[4], ov[5], ov[6], ov[7]};
    ((float4*)(outF + (size_t)row * 512))[t * 2] = o0;
    ((float4*)(outF + (size_t)row * 512))[t * 2 + 1] = o1;
  } else {
    __align__(16) ushort h8[8];
#pragma unroll
    for (int e = 0; e < 8; ++e) h8[e] = f2bf(ov[e]);
    *(bf16x8*)(outH + (size_t)row * 512 + c) = *(bf16x8*)h8;
  }
}

// ---------------------------------------------------------------------------
extern "C" void kernel_launch(void* const* d_in, const int* in_sizes, int n_in,
                              void* d_out, int out_size, void* d_ws,
                              size_t ws_size, hipStream_t stream) {
  const float* x = (const float*)d_in[0];
  const float* patch_w = (const float*)d_in[1];
  const float* patch_b = (const float*)d_in[2];
  const float* pnorm_w = (const float*)d_in[3];
  const float* pnorm_b = (const float*)d_in[4];
  const float* s0_n2w = (const float*)d_in[5];
  const float* s0_n2b = (const float*)d_in[6];
  const float* s0_f1w = (const float*)d_in[7];
  const float* s0_f1b = (const float*)d_in[8];
  const float* s0_f2w = (const float*)d_in[9];
  const float* s0_f2b = (const float*)d_in[10];
  const float* m0_nw = (const float*)d_in[11];
  const float* m0_nb = (const float*)d_in[12];
  const float* m0_rw = (const float*)d_in[13];
  const float* s1_n2w = (const float*)d_in[14];
  const float* s1_n2b = (const float*)d_in[15];
  const float* s1_f1w = (const float*)d_in[16];
  const float* s1_f1b = (const float*)d_in[17];
  const float* s1_f2w = (const float*)d_in[18];
  const float* s1_f2b = (const float*)d_in[19];
  const float* m1_nw = (const float*)d_in[20];
  const float* m1_nb = (const float*)d_in[21];
  const float* m1_rw = (const float*)d_in[22];
  const float* pos_embed = (const float*)d_in[23];
  const float* mb_n1w = (const float*)d_in[24];
  const float* mb_n1b = (const float*)d_in[25];
  const float* mb_qkvw = (const float*)d_in[26];
  const float* mb_qkvb = (const float*)d_in[27];
  const float* mb_rpb = (const float*)d_in[28];
  const float* mb_projw = (const float*)d_in[29];
  const float* mb_projb = (const float*)d_in[30];
  const float* mb_n2w = (const float*)d_in[31];
  const float* mb_n2b = (const float*)d_in[32];
  const float* mb_f1w = (const float*)d_in[33];
  const float* mb_f1b = (const float*)d_in[34];
  const float* mb_f2w = (const float*)d_in[35];
  const float* mb_f2b = (const float*)d_in[36];
  const float* fnorm_w = (const float*)d_in[37];
  const float* fnorm_b = (const float*)d_in[38];
  const int* rpe = (const int*)d_in[39];

  // Workspace (235 MB of ~320 MiB):
  float* Xa = (float*)d_ws;
  ushort* BufB = (ushort*)(Xa + 8388608);
  ushort* BufC = (ushort*)(Xa + 12582912);
  ushort* Qkvh = BufC;
  ushort* F1h = BufC + 14680064;
  ushort* Wall = (ushort*)(Xa + 25165824);
  ushort* WallBig = (ushort*)(Xa + 27262976);

#define CONVH(src, cnt, dh)                                              \
  convh_kernel<<<((cnt) / 4 + 255) / 256, 256, 0, stream>>>(src, dh, (cnt) / 4)

  // Pre-convert ALL 20 main layers' weights (one pass per weight type).
  convmain_kernel<<<(20 * 196608 + 255) / 256, 256, 0, stream>>>(
      mb_qkvw, WallBig, 196608, 0, 20 * 196608);
  convmain_kernel<<<(20 * 65536 + 255) / 256, 256, 0, stream>>>(
      mb_projw, WallBig, 65536, 196608, 20 * 65536);
  convmain_kernel<<<(20 * 262144 + 255) / 256, 256, 0, stream>>>(
      mb_f1w, WallBig, 262144, 262144, 20 * 262144);
  convmain_kernel<<<(20 * 262144 + 255) / 256, 256, 0, stream>>>(
      mb_f2w, WallBig, 262144, 524288, 20 * 262144);

  // Patch embed + pnorm LN -> Xa [65536,128]
  patch_ln2_kernel<<<4096, 256, 0, stream>>>(x, patch_w, patch_b, pnorm_w,
                                             pnorm_b, Xa);

  // Stem stage 0: 8 MLP blocks, dim 128, hidden 384.
  // LN for block 0 standalone; LN for blocks 1..7 fused into f2 EP5.
  CONVH(s0_f1w, 8 * 49152, Wall);
  CONVH(s0_f2w, 8 * 49152, Wall + 393216);
  lnC_kernel<128><<<65536 / 4, 256, 0, stream>>>(Xa, s0_n2w, s0_n2b, BufB);
  for (int i = 0; i < 8; ++i) {
    mgemm4_kernel<3, 128><<<(65536 / 128) * (384 / 128), 256, 0, stream>>>(
        BufB, Wall + i * 49152, s0_f1b + i * 384, nullptr, nullptr, BufC,
        nullptr, nullptr, 65536, 384, 128);
    if (i < 7) {
      mgemm4_kernel<5, 64><<<(65536 / 64) * (128 / 128), 256, 0, stream>>>(
          BufC, Wall + 393216 + i * 49152, s0_f2b + i * 128, Xa, Xa, BufB,
          s0_n2w + (i + 1) * 128, s0_n2b + (i + 1) * 128, 65536, 128, 384);
    } else {
      mgemm4_kernel<2, 64><<<(65536 / 64) * (128 / 128), 256, 0, stream>>>(
          BufC, Wall + 393216 + i * 49152, s0_f2b + i * 128, Xa, Xa, nullptr,
          nullptr, nullptr, 65536, 128, 384);
    }
  }
  // Merge 0 -> BufB [16384,512] bf16 -> GEMM -> Xa [16384,256]
  merge_ln_kernel<0><<<16384, 256, 0, stream>>>(Xa, m0_nw, m0_nb, BufB);
  CONVH(m0_rw, 131072, Wall);
  mgemm4_kernel<0, 128><<<(16384 / 128) * (256 / 128), 256, 0, stream>>>(
      BufB, Wall, nullptr, nullptr, Xa, nullptr, nullptr, nullptr, 16384, 256,
      512);

  // Stem stage 1: 8 MLP blocks, dim 256, hidden 768
  CONVH(s1_f1w, 8 * 196608, Wall);
  CONVH(s1_f2w, 8 * 196608, Wall + 1572864);
  for (int i = 0; i < 8; ++i) {
    lnC_kernel<256><<<16384 / 4, 256, 0, stream>>>(Xa, s1_n2w + i * 256,
                                                   s1_n2b + i * 256, BufB);
    mgemm4_kernel<3, 128><<<(16384 / 128) * (768 / 128), 256, 0, stream>>>(
        BufB, Wall + i * 196608, s1_f1b + i * 768, nullptr, nullptr, BufC,
        nullptr, nullptr, 16384, 768, 256);
    mgemm4_kernel<2, 64><<<(16384 / 64) * (256 / 128), 256, 0, stream>>>(
        BufC, Wall + 1572864 + i * 196608, s1_f2b + i * 256, Xa, Xa, nullptr,
        nullptr, nullptr, 16384, 256, 768);
  }
  // Merge 1 -> BufB [4096,1024] bf16 -> GEMM + pos -> Xa [4096,512]
  merge_ln_kernel<1><<<4096, 256, 0, stream>>>(Xa, m1_nw, m1_nb, BufB);
  CONVH(m1_rw, 524288, Wall);
  mgemm4_kernel<1, 32><<<(4096 / 32) * (512 / 128), 256, 0, stream>>>(
      BufB, Wall, nullptr, pos_embed, Xa, nullptr, nullptr, nullptr, 4096, 512,
      1024);

  // 20 main attention blocks. Per-layer weights at WallBig + l*3145728.
  // proj and f2 use BM=32 (grid 512 = 2 blocks/CU vs 256 = 1 at BM=64).
  for (int l = 0; l < 20; ++l) {
    ushort* Wl = WallBig + (size_t)l * 3145728;
    ln512_kernel<1><<<1024, 256, 0, stream>>>(Xa, mb_n1w + l * 512,
                                              mb_n1b + l * 512, nullptr, BufB);
    mgemm4_kernel<4, 64><<<(4096 / 64) * (1536 / 128), 256, 0, stream>>>(
        BufB, Wl, mb_qkvb + l * 1536, nullptr, nullptr, Qkvh, nullptr, nullptr,
        4096, 1536, 512);
    attn_fused2_kernel<<<512, 256, 0, stream>>>(Qkvh, mb_rpb + l * 7688, rpe,
                                                BufB);
    mgemm4_kernel<2, 32><<<(4096 / 32) * (512 / 128), 256, 0, stream>>>(
        BufB, Wl + 786432, mb_projb + l * 512, Xa, Xa, nullptr, nullptr,
        nullptr, 4096, 512, 512);
    ln512_kernel<1><<<1024, 256, 0, stream>>>(Xa, mb_n2w + l * 512,
                                              mb_n2b + l * 512, nullptr, BufB);
    mgemm4_kernel<3, 128><<<(4096 / 128) * (2048 / 128), 256, 0, stream>>>(
        BufB, Wl + 1048576, mb_f1b + l * 2048, nullptr, nullptr, F1h, nullptr,
        nullptr, 4096, 2048, 512);
    mgemm4_kernel<2, 32><<<(4096 / 32) * (512 / 128), 256, 0, stream>>>(
        F1h, Wl + 2097152, mb_f2b + l * 512, Xa, Xa, nullptr, nullptr, nullptr,
        4096, 512, 2048);
  }
  // Final LN -> d_out (f32)
  ln512_kernel<0><<<1024, 256, 0, stream>>>(Xa, fnorm_w, fnorm_b,
                                            (float*)d_out, nullptr);
}

// Round 25
// 3181.584 us; speedup vs baseline: 1.1192x; 1.0259x over previous
//
#include <hip/hip_runtime.h>
#include <math.h>

#define EPSV 1e-5f

typedef __attribute__((ext_vector_type(8))) short bf16x8;
typedef __attribute__((ext_vector_type(4))) float f32x4;
typedef unsigned short ushort;

__device__ inline ushort f2bf(float x) {
  unsigned u = __builtin_bit_cast(unsigned, x);
  u += 0x7FFFu + ((u >> 16) & 1u);
  return (ushort)(u >> 16);
}

// async global->LDS, 16 bytes per lane; dest = wave-uniform base + lane*16
#define GLOAD16(lptr, gptr)                                              \
  __builtin_amdgcn_global_load_lds(                                      \
      (const __attribute__((address_space(1))) unsigned int*)(gptr),     \
      (__attribute__((address_space(3))) unsigned int*)(lptr), 16, 0, 0)

// ---------------------------------------------------------------------------
// f32 -> bf16 plane conversion (contiguous). n4 = count/4.
// ---------------------------------------------------------------------------
__global__ __launch_bounds__(256) void convh_kernel(
    const float* __restrict__ in, ushort* __restrict__ hi, int n4) {
  int i = blockIdx.x * 256 + threadIdx.x;
  if (i >= n4) return;
  float4 v = ((const float4*)in)[i];
  float vv[4] = {v.x, v.y, v.z, v.w};
  unsigned hw[4];
#pragma unroll
  for (int e = 0; e < 4; ++e) hw[e] = f2bf(vv[e]);
  ((uint2*)hi)[i] = make_uint2(hw[0] | (hw[1] << 16), hw[2] | (hw[3] << 16));
}

// ---------------------------------------------------------------------------
// f32 -> bf16 for all 20 main layers of one weight type, strided dst.
// ---------------------------------------------------------------------------
__global__ __launch_bounds__(256) void convmain_kernel(
    const float* __restrict__ src, ushort* __restrict__ dst, int perLayer4,
    int dstOff4, int n4) {
  int i = blockIdx.x * 256 + threadIdx.x;
  if (i >= n4) return;
  int l = i / perLayer4;
  int r = i - l * perLayer4;
  float4 v = ((const float4*)src)[i];
  float vv[4] = {v.x, v.y, v.z, v.w};
  unsigned hw[4];
#pragma unroll
  for (int e = 0; e < 4; ++e) hw[e] = f2bf(vv[e]);
  ((uint2*)dst)[(size_t)l * 786432 + dstOff4 + r] =
      make_uint2(hw[0] | (hw[1] << 16), hw[2] | (hw[3] << 16));
}

// ---------------------------------------------------------------------------
// Patch embed + pnorm LN v2. Block = (b, n): 16 tokens x 128 ch, 256 thr.
// ---------------------------------------------------------------------------
__global__ __launch_bounds__(256) void patch_ln2_kernel(
    const float* __restrict__ x, const float* __restrict__ pw,
    const float* __restrict__ pbias, const float* __restrict__ nw,
    const float* __restrict__ nb, float* __restrict__ out) {
  int bid = blockIdx.x;  // b*256 + n
  int b = bid >> 8, n = bid & 255;
  int py = (n >> 4) * 16, px0 = (n & 15) * 16;
  __shared__ float xin[3][16][16];
  __shared__ float wls[128][52];
  __shared__ float pbs[128];
  int tid = threadIdx.x;
  if (tid < 192) {
    int ci = tid / 64, rr = (tid % 64) >> 2, c4 = tid & 3;
    const float* src =
        x + ((size_t)(b * 3 + ci) * 256 + (py + rr)) * 256 + px0 + c4 * 4;
    *(float4*)&xin[ci][rr][c4 * 4] = *(const float4*)src;
  }
  for (int idx = tid; idx < 6144; idx += 256) {
    int c = idx / 48, q = idx % 48;
    wls[c][q] = pw[c * 48 + q];
  }
  if (tid < 128) pbs[tid] = pbias[tid];
  __syncthreads();

  int tt = tid >> 4, cg = tid & 15;
  int ii = tt >> 2, jj = tt & 3;
  float xv[48];
#pragma unroll
  for (int ci = 0; ci < 3; ++ci)
#pragma unroll
    for (int dy = 0; dy < 4; ++dy)
#pragma unroll
      for (int dx = 0; dx < 4; ++dx)
        xv[ci * 16 + dy * 4 + dx] = xin[ci][ii * 4 + dy][jj * 4 + dx];

  float o[8];
#pragma unroll
  for (int e = 0; e < 8; ++e) {
    int c = cg + e * 16;
    float a = pbs[c];
#pragma unroll
    for (int q4 = 0; q4 < 12; ++q4) {
      float4 w4 = *(const float4*)&wls[c][q4 * 4];
      a += w4.x * xv[q4 * 4] + w4.y * xv[q4 * 4 + 1] + w4.z * xv[q4 * 4 + 2] +
           w4.w * xv[q4 * 4 + 3];
    }
    o[e] = a;
  }
  float s = 0.f;
#pragma unroll
  for (int e = 0; e < 8; ++e) s += o[e];
#pragma unroll
  for (int off = 8; off > 0; off >>= 1) s += __shfl_xor(s, off, 16);
  float mean = s * (1.0f / 128.0f);
  float sq = 0.f;
#pragma unroll
  for (int e = 0; e < 8; ++e) {
    float d = o[e] - mean;
    sq += d * d;
  }
#pragma unroll
  for (int off = 8; off > 0; off >>= 1) sq += __shfl_xor(sq, off, 16);
  float rstd = rsqrtf(sq * (1.0f / 128.0f) + EPSV);
  size_t base = ((size_t)bid * 16 + tt) * 128;
#pragma unroll
  for (int e = 0; e < 8; ++e) {
    int c = cg + e * 16;
    out[base + c] = (o[e] - mean) * rstd * nw[c] + nb[c];
  }
}

// ---------------------------------------------------------------------------
// LayerNorm over C (128/256), one wave per row, 4 rows/block -> bf16 plane.
// ---------------------------------------------------------------------------
template <int C>
__global__ __launch_bounds__(256) void lnC_kernel(
    const float* __restrict__ X, const float* __restrict__ w,
    const float* __restrict__ bb, ushort* __restrict__ outH) {
  constexpr int NV = C / 64;
  int wave = threadIdx.x >> 6, lane = threadIdx.x & 63;
  int row = blockIdx.x * 4 + wave;
  const float* xr = X + (size_t)row * C + lane * NV;
  float v[NV];
  if (NV == 2) {
    float2 t2 = *(const float2*)xr;
    v[0] = t2.x; v[1] = t2.y;
  } else {
#pragma unroll
    for (int q = 0; q < NV; q += 4) {
      float4 t4 = *(const float4*)(xr + q);
      v[q] = t4.x; v[q + 1] = t4.y; v[q + 2] = t4.z; v[q + 3] = t4.w;
    }
  }
  float s = 0.f;
#pragma unroll
  for (int q = 0; q < NV; ++q) s += v[q];
#pragma unroll
  for (int o = 32; o > 0; o >>= 1) s += __shfl_xor(s, o, 64);
  float mean = s * (1.0f / C);
  float sq = 0.f;
#pragma unroll
  for (int q = 0; q < NV; ++q) {
    float d = v[q] - mean;
    sq += d * d;
  }
#pragma unroll
  for (int o = 32; o > 0; o >>= 1) sq += __shfl_xor(sq, o, 64);
  float rstd = rsqrtf(sq * (1.0f / C) + EPSV);
#pragma unroll
  for (int q = 0; q < NV; ++q) {
    int c = lane * NV + q;
    outH[(size_t)row * C + c] = f2bf((v[q] - mean) * rstd * w[c] + bb[c]);
  }
}

// ---------------------------------------------------------------------------
// Patch merge gather + LN -> bf16 plane.
// ---------------------------------------------------------------------------
template <int MODE>
__global__ __launch_bounds__(256) void merge_ln_kernel(
    const float* __restrict__ Xin, const float* __restrict__ nw,
    const float* __restrict__ nb, ushort* __restrict__ outH) {
  constexpr int CM = MODE ? 1024 : 512;
  constexpr int NE = CM / 256;
  int ot = blockIdx.x;
  int tid = threadIdx.x;
  __shared__ float redA[4];
  __shared__ float redB[4];

  float v[NE];
#pragma unroll
  for (int e = 0; e < NE; ++e) {
    int cp = tid + e * 256;
    if (MODE == 0) {
      int b = ot >> 10, r = ot & 1023;
      int n = r >> 2, di = (r >> 1) & 1, dj = r & 1;
      int q = cp >> 7, c = cp & 127;
      int i = 2 * di + (q & 1), j = 2 * dj + (q >> 1);
      v[e] = Xin[((b * 256 + n) * 16 + i * 4 + j) * 128 + c];
    } else {
      int b = ot >> 8, n = ot & 255;
      int q = cp >> 8, c = cp & 255;
      int di = q & 1, dj = q >> 1;
      v[e] = Xin[((b * 256 + n) * 4 + di * 2 + dj) * 256 + c];
    }
  }
  float s = 0.f;
#pragma unroll
  for (int e = 0; e < NE; ++e) s += v[e];
#pragma unroll
  for (int o = 32; o > 0; o >>= 1) s += __shfl_xor(s, o, 64);
  if ((tid & 63) == 0) redA[tid >> 6] = s;
  __syncthreads();
  float mean = (redA[0] + redA[1] + redA[2] + redA[3]) * (1.0f / CM);
  float sq = 0.f;
#pragma unroll
  for (int e = 0; e < NE; ++e) {
    float d = v[e] - mean;
    sq += d * d;
  }
#pragma unroll
  for (int o = 32; o > 0; o >>= 1) sq += __shfl_xor(sq, o, 64);
  if ((tid & 63) == 0) redB[tid >> 6] = sq;
  __syncthreads();
  float var = (redB[0] + redB[1] + redB[2] + redB[3]) * (1.0f / CM);
  float rstd = rsqrtf(var + EPSV);
#pragma unroll
  for (int e = 0; e < NE; ++e) {
    int cp = tid + e * 256;
    outH[(size_t)ot * CM + cp] = f2bf((v[e] - mean) * rstd * nw[cp] + nb[cp]);
  }
}

// ---------------------------------------------------------------------------
// bf16 MFMA GEMM v5: BK=64, XOR-swizzled LDS, LDS-staged vectorized epilogue.
// EP 0: bias->f32. EP 1: +pos->f32. EP 2: +extra->f32 (residual).
// EP 3: gelu->bf16. EP 4: qkv->bf16 (Q cols x0.125).
// EP 5: residual->f32 AND fused next-block LN->bf16 (requires N==128, nb==1).
// BM in {32, 64, 128}.
// ---------------------------------------------------------------------------
template <int EP, int BM>
__global__ __launch_bounds__(256) void mgemm4_kernel(
    const ushort* __restrict__ Ah, const ushort* __restrict__ Wh,
    const float* __restrict__ bias, const float* __restrict__ extra,
    float* __restrict__ outF, ushort* __restrict__ outH,
    const float* __restrict__ lnw, const float* __restrict__ lnb, int M, int N,
    int K) {
  constexpr int NI = BM / 32;
  constexpr int ASH = BM * 64;  // A tile shorts
  constexpr int LSZ =
      (ASH + 8192 > ((BM == 32) ? 32 * 136 * 2 : BM * 136))
          ? (ASH + 8192)
          : ((BM == 32) ? 32 * 136 * 2 : BM * 136);
  __shared__ __align__(16) ushort Lds[LSZ];
  int nb = N >> 7;
  int bx = blockIdx.x % nb, by = blockIdx.x / nb;
  int tid = threadIdx.x;
  int wv = tid >> 6, lane = tid & 63;
  int srow = tid >> 3;
  int scol = ((tid & 7) ^ (srow & 7)) << 3;  // source-side swizzle (shorts)
  const ushort* aS = Ah + (size_t)(by * BM + srow) * K + scol;
  const ushort* wS = Wh + (size_t)(bx * 128 + srow) * K + scol;
  ushort* dA = Lds + wv * 512;
  ushort* dW = Lds + ASH + wv * 512;

  int wm = (wv >> 1) * (BM / 2), wn = (wv & 1) * 64;
  int fr = lane & 15, fq = lane >> 4;
  int rsw = fr & 7;  // read-side swizzle key

  f32x4 acc[NI][4];
#pragma unroll
  for (int i = 0; i < NI; ++i)
#pragma unroll
    for (int j = 0; j < 4; ++j) acc[i][j] = {0.f, 0.f, 0.f, 0.f};

  for (int k0 = 0; k0 < K; k0 += 64) {
#pragma unroll
    for (int q = 0; q < (BM + 31) / 32; ++q)
      GLOAD16(dA + q * 2048, aS + (size_t)q * 32 * K + k0);
#pragma unroll
    for (int q = 0; q < 4; ++q)
      GLOAD16(dW + q * 2048, wS + (size_t)q * 32 * K + k0);
    __syncthreads();

#pragma unroll
    for (int kh = 0; kh < 2; ++kh) {
      bf16x8 fa[NI], fb[4];
#pragma unroll
      for (int i = 0; i < NI; ++i) {
        int row = wm + i * 16 + fr;
        fa[i] = *(const bf16x8*)(Lds + row * 64 + ((((kh << 2) + fq) ^ rsw) << 3));
      }
#pragma unroll
      for (int j = 0; j < 4; ++j) {
        int row = wn + j * 16 + fr;
        fb[j] = *(const bf16x8*)(Lds + ASH + row * 64 +
                                 ((((kh << 2) + fq) ^ rsw) << 3));
      }
#pragma unroll
      for (int i = 0; i < NI; ++i)
#pragma unroll
        for (int j = 0; j < 4; ++j)
          acc[i][j] = __builtin_amdgcn_mfma_f32_16x16x32_bf16(fa[i], fb[j],
                                                              acc[i][j], 0, 0,
                                                              0);
    }
    __syncthreads();
  }

  int row0 = by * BM;
  int col0 = bx * 128;
  if (EP == 3 || EP == 4) {
    ushort* LdsO = Lds;
#pragma unroll
    for (int j = 0; j < 4; ++j) {
      int col = wn + j * 16 + fr;
      float bvv = bias ? bias[col0 + col] : 0.f;
      bool sc = (EP == 4) && (col0 + col < 512);
#pragma unroll
      for (int i = 0; i < NI; ++i) {
#pragma unroll
        for (int e = 0; e < 4; ++e) {
          int rl = wm + i * 16 + fq * 4 + e;
          float o = acc[i][j][e] + bvv;
          if (EP == 3)
            o = 0.5f * o * (1.0f + erff(o * 0.70710678118654752f));
          else if (sc)
            o *= 0.125f;
          LdsO[rl * 136 + col] = f2bf(o);
        }
      }
    }
    __syncthreads();
#pragma unroll
    for (int p = 0; p < BM / 16; ++p) {
      int ch = p * 256 + tid;
      int r = ch >> 4, cc = (ch & 15) * 8;
      *(uint4*)&outH[(size_t)(row0 + r) * N + col0 + cc] =
          *(const uint4*)&LdsO[r * 136 + cc];
    }
  } else {
    float* LdsF = (float*)Lds;
    int strip = wv >> 1;
#pragma unroll
    for (int i = 0; i < NI; ++i) {
#pragma unroll
      for (int j = 0; j < 4; ++j) {
        int col = wn + j * 16 + fr;
        float bvv = bias ? bias[col0 + col] : 0.f;
#pragma unroll
        for (int e = 0; e < 4; ++e)
          LdsF[(strip * 16 + fq * 4 + e) * 136 + col] = acc[i][j][e] + bvv;
      }
      __syncthreads();
#pragma unroll
      for (int p = 0; p < 4; ++p) {
        int c = p * 256 + tid;  // 0..1023
        int st = c >> 9;
        int rem = c & 511;
        int r = rem >> 5, cc = (rem & 31) * 4;
        int grow = row0 + st * (BM / 2) + i * 16 + r;
        float4 v = *(const float4*)&LdsF[(st * 16 + r) * 136 + cc];
        if (EP == 1) {
          float4 e4 =
              *(const float4*)&extra[(size_t)(grow & 255) * N + col0 + cc];
          v.x += e4.x; v.y += e4.y; v.z += e4.z; v.w += e4.w;
        } else if (EP == 2 || EP == 5) {
          float4 e4 = *(const float4*)&extra[(size_t)grow * N + col0 + cc];
          v.x += e4.x; v.y += e4.y; v.z += e4.z; v.w += e4.w;
        }
        *(float4*)&outF[(size_t)grow * N + col0 + cc] = v;
        if (EP == 5) {
          // fused next-block LN (N==128, nb==1): each row's 128 cols live in
          // a 32-lane group (threads r*32..r*32+31 of this wave).
          float s1 = v.x + v.y + v.z + v.w;
#pragma unroll
          for (int o = 16; o > 0; o >>= 1) s1 += __shfl_xor(s1, o, 32);
          float mean = s1 * (1.0f / 128.0f);
          float dx = v.x - mean, dy = v.y - mean, dz = v.z - mean,
                dw = v.w - mean;
          float s2 = dx * dx + dy * dy + dz * dz + dw * dw;
#pragma unroll
          for (int o = 16; o > 0; o >>= 1) s2 += __shfl_xor(s2, o, 32);
          float rstd = rsqrtf(s2 * (1.0f / 128.0f) + EPSV);
          unsigned h0 = f2bf(dx * rstd * lnw[cc] + lnb[cc]);
          unsigned h1 = f2bf(dy * rstd * lnw[cc + 1] + lnb[cc + 1]);
          unsigned h2 = f2bf(dz * rstd * lnw[cc + 2] + lnb[cc + 2]);
          unsigned h3 = f2bf(dw * rstd * lnw[cc + 3] + lnb[cc + 3]);
          *(uint2*)&outH[(size_t)grow * N + cc] =
              make_uint2(h0 | (h1 << 16), h2 | (h3 << 16));
        }
      }
      __syncthreads();
    }
  }
}

// ---------------------------------------------------------------------------
// Fused MFMA attention: scores + softmax + PV in one kernel.
// Block = (b, h, 64 q-rows), grid 512, 256 thr. LDS ~77 KB -> 2 blocks/CU.
// ---------------------------------------------------------------------------
__global__ __launch_bounds__(256) void attn_fused2_kernel(
    const ushort* __restrict__ qkvh, const float* __restrict__ rpb,
    const int* __restrict__ rpe, ushort* __restrict__ outH) {
  int bid = blockIdx.x;
  int qc = bid & 3, bh = bid >> 2;
  int b = bh >> 3, h = bh & 7;
  int n0 = qc * 64;
  int tid = threadIdx.x;
  int wv = tid >> 6, lane = tid & 63;
  int fr = lane & 15, fq = lane >> 4;
  __shared__ __align__(16) ushort Qs[64 * 64];
  __shared__ __align__(16) ushort Ks[256 * 64];   // K, then P [64][256]
  __shared__ __align__(16) ushort Vt[64 * 256];
  __shared__ float rpbh[961];
  __shared__ float red[64][4];

  int srow = tid >> 3;
  int sc = ((tid & 7) ^ (srow & 7)) << 3;
  const ushort* Qg = qkvh + (size_t)(b * 256 + n0 + srow) * 1536 + h * 64 + sc;
  GLOAD16(Qs + wv * 512, Qg);
  GLOAD16(Qs + 2048 + wv * 512, Qg + (size_t)32 * 1536);
  const ushort* Kg = qkvh + (size_t)(b * 256 + srow) * 1536 + 512 + h * 64 + sc;
#pragma unroll
  for (int q = 0; q < 8; ++q)
    GLOAD16(Ks + q * 2048 + wv * 512, Kg + (size_t)q * 32 * 1536);
#pragma unroll
  for (int pass = 0; pass < 4; ++pass) {
    int m = pass * 64 + (tid >> 2);
    int sg = (tid & 3) * 16;
    const ushort* Vg = qkvh + (size_t)(b * 256 + m) * 1536 + 1024 + h * 64 + sg;
    ushort tmp[16];
    *(uint4*)tmp = *(const uint4*)Vg;
    *(uint4*)(tmp + 8) = *(const uint4*)(Vg + 8);
    int ch = m >> 3, ml = m & 7;
#pragma unroll
    for (int e = 0; e < 16; ++e) {
      int d = sg + e;
      int cs = (ch & 24) | ((ch & 7) ^ (d & 7));
      Vt[d * 256 + cs * 8 + ml] = tmp[e];
    }
  }
  for (int i = tid; i < 961; i += 256) rpbh[i] = rpb[i * 8 + h];
  __syncthreads();

  f32x4 acc[4][4];
#pragma unroll
  for (int i = 0; i < 4; ++i)
#pragma unroll
    for (int j = 0; j < 4; ++j) acc[i][j] = {0.f, 0.f, 0.f, 0.f};
#pragma unroll
  for (int kh = 0; kh < 2; ++kh) {
    bf16x8 fa[4], fb[4];
#pragma unroll
    for (int i = 0; i < 4; ++i) {
      int row = i * 16 + fr;
      fa[i] = *(const bf16x8*)(Qs + row * 64 +
                               ((((kh << 2) + fq) ^ (row & 7)) << 3));
    }
#pragma unroll
    for (int j = 0; j < 4; ++j) {
      int row = wv * 64 + j * 16 + fr;
      fb[j] = *(const bf16x8*)(Ks + row * 64 +
                               ((((kh << 2) + fq) ^ (row & 7)) << 3));
    }
#pragma unroll
    for (int i = 0; i < 4; ++i)
#pragma unroll
      for (int j = 0; j < 4; ++j)
        acc[i][j] = __builtin_amdgcn_mfma_f32_16x16x32_bf16(fa[i], fb[j],
                                                            acc[i][j], 0, 0, 0);
  }

  float sreg[4][4][4];  // [i][j][e]
#pragma unroll
  for (int i = 0; i < 4; ++i)
#pragma unroll
    for (int e = 0; e < 4; ++e) {
      int n = n0 + i * 16 + fq * 4 + e;
#pragma unroll
      for (int j = 0; j < 4; ++j) {
        int m = wv * 64 + j * 16 + fr;
        sreg[i][j][e] = acc[i][j][e] + rpbh[rpe[n * 256 + m]];
      }
    }

  float rmax[4][4];
#pragma unroll
  for (int i = 0; i < 4; ++i)
#pragma unroll
    for (int e = 0; e < 4; ++e) {
      float mx = fmaxf(fmaxf(sreg[i][0][e], sreg[i][1][e]),
                       fmaxf(sreg[i][2][e], sreg[i][3][e]));
#pragma unroll
      for (int o = 8; o > 0; o >>= 1) mx = fmaxf(mx, __shfl_xor(mx, o, 16));
      if (fr == 0) red[i * 16 + fq * 4 + e][wv] = mx;
    }
  __syncthreads();  // also: all K reads complete beyond this point
#pragma unroll
  for (int i = 0; i < 4; ++i)
#pragma unroll
    for (int e = 0; e < 4; ++e) {
      int row = i * 16 + fq * 4 + e;
      rmax[i][e] = fmaxf(fmaxf(red[row][0], red[row][1]),
                         fmaxf(red[row][2], red[row][3]));
    }
  __syncthreads();
  float rinv[4][4];
#pragma unroll
  for (int i = 0; i < 4; ++i)
#pragma unroll
    for (int e = 0; e < 4; ++e) {
      float sm = 0.f;
#pragma unroll
      for (int j = 0; j < 4; ++j) {
        sreg[i][j][e] = expf(sreg[i][j][e] - rmax[i][e]);
        sm += sreg[i][j][e];
      }
#pragma unroll
      for (int o = 8; o > 0; o >>= 1) sm += __shfl_xor(sm, o, 16);
      if (fr == 0) red[i * 16 + fq * 4 + e][wv] = sm;
    }
  __syncthreads();
#pragma unroll
  for (int i = 0; i < 4; ++i)
#pragma unroll
    for (int e = 0; e < 4; ++e) {
      int row = i * 16 + fq * 4 + e;
      rinv[i][e] =
          1.0f / (red[row][0] + red[row][1] + red[row][2] + red[row][3]);
    }
  ushort* Ps = Ks;
#pragma unroll
  for (int i = 0; i < 4; ++i)
#pragma unroll
    for (int e = 0; e < 4; ++e) {
      int qrow = i * 16 + fq * 4 + e;
#pragma unroll
      for (int j = 0; j < 4; ++j) {
        int m = wv * 64 + j * 16 + fr;
        int ch = m >> 3, t = m & 7;
        int cs = (ch & 24) | ((ch & 7) ^ (qrow & 7));
        Ps[qrow * 256 + cs * 8 + t] = f2bf(sreg[i][j][e] * rinv[i][e]);
      }
    }
  __syncthreads();

  f32x4 pacc[4];
#pragma unroll
  for (int i = 0; i < 4; ++i) pacc[i] = {0.f, 0.f, 0.f, 0.f};
  int dbase = wv * 16;
#pragma unroll
  for (int ks = 0; ks < 8; ++ks) {
    int ch = (ks << 2) + fq;
    bf16x8 fb;
    {
      int row = dbase + fr;
      int cs = (ch & 24) | ((ch & 7) ^ (row & 7));
      fb = *(const bf16x8*)(Vt + row * 256 + cs * 8);
    }
    bf16x8 fa[4];
#pragma unroll
    for (int i = 0; i < 4; ++i) {
      int row = i * 16 + fr;
      int cs = (ch & 24) | ((ch & 7) ^ (row & 7));
      fa[i] = *(const bf16x8*)(Ps + row * 256 + cs * 8);
    }
#pragma unroll
    for (int i = 0; i < 4; ++i)
      pacc[i] = __builtin_amdgcn_mfma_f32_16x16x32_bf16(fa[i], fb, pacc[i], 0,
                                                        0, 0);
  }
#pragma unroll
  for (int i = 0; i < 4; ++i)
#pragma unroll
    for (int e = 0; e < 4; ++e) {
      int q = i * 16 + fq * 4 + e;
      outH[(size_t)(b * 256 + n0 + q) * 512 + h * 64 + dbase + fr] =
          f2bf(pacc[i][e]);
    }
}

// ---------------------------------------------------------------------------
// LayerNorm over 512, wave per row, 4 rows/block. HL=0 f32, HL=1 bf16 plane.
// ---------------------------------------------------------------------------
template <int HL>
__global__ __launch_bounds__(256) void ln512_kernel(
    const float* __restrict__ X, const float* __restrict__ w,
    const float* __restrict__ bb, float* __restrict__ outF,
    ushort* __restrict__ outH) {
  int row = blockIdx.x * 4 + (threadIdx.x >> 6);
  int t = threadIdx.x & 63;
  const float4* xr = (const float4*)(X + (size_t)row * 512);
  float4 v0 = xr[t * 2], v1 = xr[t * 2 + 1];
  float s = v0.x + v0.y + v0.z + v0.w + v1.x + v1.y + v1.z + v1.w;
#pragma unroll
  for (int o = 32; o > 0; o >>= 1) s += __shfl_xor(s, o, 64);
  float mean = s * (1.0f / 512.0f);
  float dv[8] = {v0.x - mean, v0.y - mean, v0.z - mean, v0.w - mean,
                 v1.x - mean, v1.y - mean, v1.z - mean, v1.w - mean};
  float sq = 0.f;
#pragma unroll
  for (int e = 0; e < 8; ++e) sq += dv[e] * dv[e];
#pragma unroll
  for (int o = 32; o > 0; o >>= 1) sq += __shfl_xor(sq, o, 64);
  float rstd = rsqrtf(sq * (1.0f / 512.0f) + EPSV);
  int c = t * 8;
  float ov[8];
#pragma unroll
  for (int e = 0; e < 8; ++e) ov[e] = dv[e] * rstd * w[c + e] + bb[c + e];
  if (HL == 0) {
    float4 o0 = {ov[0], ov[1], ov[2], ov[3]};
    float4 o1 = {ov[4], ov[5], ov[6], ov[7]};
    ((float4*)(outF + (size_t)row * 512))[t * 2] = o0;
    ((float4*)(outF + (size_t)row * 512))[t * 2 + 1] = o1;
  } else {
    __align__(16) ushort h8[8];
#pragma unroll
    for (int e = 0; e < 8; ++e) h8[e] = f2bf(ov[e]);
    *(bf16x8*)(outH + (size_t)row * 512 + c) = *(bf16x8*)h8;
  }
}

// ---------------------------------------------------------------------------
extern "C" void kernel_launch(void* const* d_in, const int* in_sizes, int n_in,
                              void* d_out, int out_size, void* d_ws,
                              size_t ws_size, hipStream_t stream) {
  const float* x = (const float*)d_in[0];
  const float* patch_w = (const float*)d_in[1];
  const float* patch_b = (const float*)d_in[2];
  const float* pnorm_w = (const float*)d_in[3];
  const float* pnorm_b = (const float*)d_in[4];
  const float* s0_n2w = (const float*)d_in[5];
  const float* s0_n2b = (const float*)d_in[6];
  const float* s0_f1w = (const float*)d_in[7];
  const float* s0_f1b = (const float*)d_in[8];
  const float* s0_f2w = (const float*)d_in[9];
  const float* s0_f2b = (const float*)d_in[10];
  const float* m0_nw = (const float*)d_in[11];
  const float* m0_nb = (const float*)d_in[12];
  const float* m0_rw = (const float*)d_in[13];
  const float* s1_n2w = (const float*)d_in[14];
  const float* s1_n2b = (const float*)d_in[15];
  const float* s1_f1w = (const float*)d_in[16];
  const float* s1_f1b = (const float*)d_in[17];
  const float* s1_f2w = (const float*)d_in[18];
  const float* s1_f2b = (const float*)d_in[19];
  const float* m1_nw = (const float*)d_in[20];
  const float* m1_nb = (const float*)d_in[21];
  const float* m1_rw = (const float*)d_in[22];
  const float* pos_embed = (const float*)d_in[23];
  const float* mb_n1w = (const float*)d_in[24];
  const float* mb_n1b = (const float*)d_in[25];
  const float* mb_qkvw = (const float*)d_in[26];
  const float* mb_qkvb = (const float*)d_in[27];
  const float* mb_rpb = (const float*)d_in[28];
  const float* mb_projw = (const float*)d_in[29];
  const float* mb_projb = (const float*)d_in[30];
  const float* mb_n2w = (const float*)d_in[31];
  const float* mb_n2b = (const float*)d_in[32];
  const float* mb_f1w = (const float*)d_in[33];
  const float* mb_f1b = (const float*)d_in[34];
  const float* mb_f2w = (const float*)d_in[35];
  const float* mb_f2b = (const float*)d_in[36];
  const float* fnorm_w = (const float*)d_in[37];
  const float* fnorm_b = (const float*)d_in[38];
  const int* rpe = (const int*)d_in[39];

  // Workspace (235 MB of ~320 MiB):
  float* Xa = (float*)d_ws;
  ushort* BufB = (ushort*)(Xa + 8388608);
  ushort* BufC = (ushort*)(Xa + 12582912);
  ushort* Qkvh = BufC;
  ushort* F1h = BufC + 14680064;
  ushort* Wall = (ushort*)(Xa + 25165824);
  ushort* WallBig = (ushort*)(Xa + 27262976);

#define CONVH(src, cnt, dh)                                              \
  convh_kernel<<<((cnt) / 4 + 255) / 256, 256, 0, stream>>>(src, dh, (cnt) / 4)

  // Pre-convert ALL 20 main layers' weights (one pass per weight type).
  convmain_kernel<<<(20 * 196608 + 255) / 256, 256, 0, stream>>>(
      mb_qkvw, WallBig, 196608, 0, 20 * 196608);
  convmain_kernel<<<(20 * 65536 + 255) / 256, 256, 0, stream>>>(
      mb_projw, WallBig, 65536, 196608, 20 * 65536);
  convmain_kernel<<<(20 * 262144 + 255) / 256, 256, 0, stream>>>(
      mb_f1w, WallBig, 262144, 262144, 20 * 262144);
  convmain_kernel<<<(20 * 262144 + 255) / 256, 256, 0, stream>>>(
      mb_f2w, WallBig, 262144, 524288, 20 * 262144);

  // Patch embed + pnorm LN -> Xa [65536,128]
  patch_ln2_kernel<<<4096, 256, 0, stream>>>(x, patch_w, patch_b, pnorm_w,
                                             pnorm_b, Xa);

  // Stem stage 0: 8 MLP blocks, dim 128, hidden 384.
  // LN for block 0 standalone; LN for blocks 1..7 fused into f2 EP5.
  CONVH(s0_f1w, 8 * 49152, Wall);
  CONVH(s0_f2w, 8 * 49152, Wall + 393216);
  lnC_kernel<128><<<65536 / 4, 256, 0, stream>>>(Xa, s0_n2w, s0_n2b, BufB);
  for (int i = 0; i < 8; ++i) {
    mgemm4_kernel<3, 128><<<(65536 / 128) * (384 / 128), 256, 0, stream>>>(
        BufB, Wall + i * 49152, s0_f1b + i * 384, nullptr, nullptr, BufC,
        nullptr, nullptr, 65536, 384, 128);
    if (i < 7) {
      mgemm4_kernel<5, 64><<<(65536 / 64) * (128 / 128), 256, 0, stream>>>(
          BufC, Wall + 393216 + i * 49152, s0_f2b + i * 128, Xa, Xa, BufB,
          s0_n2w + (i + 1) * 128, s0_n2b + (i + 1) * 128, 65536, 128, 384);
    } else {
      mgemm4_kernel<2, 64><<<(65536 / 64) * (128 / 128), 256, 0, stream>>>(
          BufC, Wall + 393216 + i * 49152, s0_f2b + i * 128, Xa, Xa, nullptr,
          nullptr, nullptr, 65536, 128, 384);
    }
  }
  // Merge 0 -> BufB [16384,512] bf16 -> GEMM -> Xa [16384,256]
  merge_ln_kernel<0><<<16384, 256, 0, stream>>>(Xa, m0_nw, m0_nb, BufB);
  CONVH(m0_rw, 131072, Wall);
  mgemm4_kernel<0, 64><<<(16384 / 64) * (256 / 128), 256, 0, stream>>>(
      BufB, Wall, nullptr, nullptr, Xa, nullptr, nullptr, nullptr, 16384, 256,
      512);

  // Stem stage 1: 8 MLP blocks, dim 256, hidden 768
  CONVH(s1_f1w, 8 * 196608, Wall);
  CONVH(s1_f2w, 8 * 196608, Wall + 1572864);
  for (int i = 0; i < 8; ++i) {
    lnC_kernel<256><<<16384 / 4, 256, 0, stream>>>(Xa, s1_n2w + i * 256,
                                                   s1_n2b + i * 256, BufB);
    mgemm4_kernel<3, 128><<<(16384 / 128) * (768 / 128), 256, 0, stream>>>(
        BufB, Wall + i * 196608, s1_f1b + i * 768, nullptr, nullptr, BufC,
        nullptr, nullptr, 16384, 768, 256);
    mgemm4_kernel<2, 32><<<(16384 / 32) * (256 / 128), 256, 0, stream>>>(
        BufC, Wall + 1572864 + i * 196608, s1_f2b + i * 256, Xa, Xa, nullptr,
        nullptr, nullptr, 16384, 256, 768);
  }
  // Merge 1 -> BufB [4096,1024] bf16 -> GEMM + pos -> Xa [4096,512]
  merge_ln_kernel<1><<<4096, 256, 0, stream>>>(Xa, m1_nw, m1_nb, BufB);
  CONVH(m1_rw, 524288, Wall);
  mgemm4_kernel<1, 32><<<(4096 / 32) * (512 / 128), 256, 0, stream>>>(
      BufB, Wall, nullptr, pos_embed, Xa, nullptr, nullptr, nullptr, 4096, 512,
      1024);

  // 20 main attention blocks. Per-layer weights at WallBig + l*3145728.
  // proj/f2 BM=32 (grid 512); f1 BM=64 (grid 1024 = 4/CU).
  for (int l = 0; l < 20; ++l) {
    ushort* Wl = WallBig + (size_t)l * 3145728;
    ln512_kernel<1><<<1024, 256, 0, stream>>>(Xa, mb_n1w + l * 512,
                                              mb_n1b + l * 512, nullptr, BufB);
    mgemm4_kernel<4, 64><<<(4096 / 64) * (1536 / 128), 256, 0, stream>>>(
        BufB, Wl, mb_qkvb + l * 1536, nullptr, nullptr, Qkvh, nullptr, nullptr,
        4096, 1536, 512);
    attn_fused2_kernel<<<512, 256, 0, stream>>>(Qkvh, mb_rpb + l * 7688, rpe,
                                                BufB);
    mgemm4_kernel<2, 32><<<(4096 / 32) * (512 / 128), 256, 0, stream>>>(
        BufB, Wl + 786432, mb_projb + l * 512, Xa, Xa, nullptr, nullptr,
        nullptr, 4096, 512, 512);
    ln512_kernel<1><<<1024, 256, 0, stream>>>(Xa, mb_n2w + l * 512,
                                              mb_n2b + l * 512, nullptr, BufB);
    mgemm4_kernel<3, 64><<<(4096 / 64) * (2048 / 128), 256, 0, stream>>>(
        BufB, Wl + 1048576, mb_f1b + l * 2048, nullptr, nullptr, F1h, nullptr,
        nullptr, 4096, 2048, 512);
    mgemm4_kernel<2, 32><<<(4096 / 32) * (512 / 128), 256, 0, stream>>>(
        F1h, Wl + 2097152, mb_f2b + l * 512, Xa, Xa, nullptr, nullptr, nullptr,
        4096, 512, 2048);
  }
  // Final LN -> d_out (f32)
  ln512_kernel<0><<<1024, 256, 0, stream>>>(Xa, fnorm_w, fnorm_b,
                                            (float*)d_out, nullptr);
}